// Round 1
// 635.870 us; speedup vs baseline: 1.0029x; 1.0029x over previous
//
#include <hip/hip_runtime.h>
#include <math.h>

#define N_NODES 50000
#define HIDD 128
#define HEADS 8
#define HDIM 16
#define NE 800000

using short8 = __attribute__((ext_vector_type(8))) short;
using f32x4 = __attribute__((ext_vector_type(4))) float;

// ---------- dtype-robust edge-index load (clamped: can never fault) ----------
__device__ __forceinline__ int load_idx(const void* ei, int is64, long long pos) {
  long long v = is64 ? ((const long long*)ei)[pos]
                     : (long long)((const int*)ei)[pos];
  unsigned uv = (unsigned)v;
  return (uv < N_NODES) ? (int)uv : 0;
}

// int64 vs int32 detect: LE int64 < 2^31 has every odd int32 word == 0.
__global__ void detect_kernel(const unsigned* __restrict__ ei_raw, int* flag) {
  __shared__ int any_nonzero;
  if (threadIdx.x == 0) any_nonzero = 0;
  __syncthreads();
  if (threadIdx.x < 128) {
    if (ei_raw[2 * threadIdx.x + 1] != 0u) atomicOr(&any_nonzero, 1);
  }
  __syncthreads();
  if (threadIdx.x == 0) *flag = any_nonzero ? 0 : 1;  // 1 => int64
}

// ---------- ws-too-small probe: absmax ~= ws_size in MB ----------
__global__ __launch_bounds__(256) void probe_kernel(float* out, int n, float mb) {
  int i = blockIdx.x * 256 + threadIdx.x;
  if (i < n) out[i] = (i == 0) ? mb : 0.f;
}

// ---------- prologue / epilogue functors ----------
struct ProNone {
  __device__ __forceinline__ float operator()(float v, int, int) const { return v; }
};
struct ProSilu {
  __device__ __forceinline__ float operator()(float v, int, int) const {
    return v / (1.f + __expf(-v));
  }
};
struct EpiNone {
  __device__ __forceinline__ float operator()(float a, int, int) const { return a; }
};
struct EpiBias {
  const float* b;  // pre-offset on host
  __device__ __forceinline__ float operator()(float a, int, int c) const { return a + b[c]; }
};
struct EpiGelu {
  const float* b;
  __device__ __forceinline__ float operator()(float a, int, int c) const {
    float t = a + b[c];
    float u = 0.7978845608028654f * (t + 0.044715f * t * t * t);
    return 0.5f * t * (1.f + tanhf(u));
  }
};
struct EpiResGate {  // xres[r,c] + gate[r,c] * (a + b[c]); gate/xres stride 128
  const float* b;
  const float* xres;
  const float* gate;
  __device__ __forceinline__ float operator()(float a, int r, int c) const {
    return xres[(size_t)r * HIDD + c] + gate[(size_t)r * HIDD + c] * (a + b[c]);
  }
};

// ---------- fused B pre-split: 8 segments, fragment-ordered bf16 hi/lo -------
// Element B[k][n] of segment s lands at:
//   lane = ((k>>3)&3)*16 + (n&15), j = k&7
//   dst  = dst_off + (((k>>5)*(N/16) + (n>>4))*64 + lane)*8 + j
struct CvTab {
  int end[8];
  int src_sel[8];
  int src_off[8];
  int ldb[8];
  int n[8];
  int dst_off[8];
};
__global__ __launch_bounds__(256) void convert_all_kernel(
    const float* __restrict__ p0, const float* __restrict__ p1,
    const float* __restrict__ p2, const float* __restrict__ p3,
    const float* __restrict__ p4, CvTab t, int total,
    unsigned short* __restrict__ hi, unsigned short* __restrict__ lo) {
  int idx = blockIdx.x * 256 + threadIdx.x;
  if (idx >= total) return;
  int s = 0;
#pragma unroll
  for (int j = 0; j < 7; j++) s += (idx >= t.end[j]) ? 1 : 0;
  int local = idx - (s ? t.end[s - 1] : 0);
  int N = t.n[s];
  int k = (unsigned)local / (unsigned)N;
  int n = local - k * N;
  const float* B;
  int sel = t.src_sel[s];
  B = (sel == 0) ? p0 : (sel == 1) ? p1 : (sel == 2) ? p2 : (sel == 3) ? p3 : p4;
  float f = B[(size_t)k * t.ldb[s] + t.src_off[s] + n];
  unsigned u = __float_as_uint(f);
  unsigned short hs = (unsigned short)(u >> 16);  // truncated bf16 hi
  float hf = __uint_as_float(u & 0xFFFF0000u);
  unsigned short ls = (unsigned short)(__float_as_uint(f - hf) >> 16);
  int lane = (((k >> 3) & 3) << 4) | (n & 15);
  int dst = t.dst_off[s] + (((k >> 5) * (N >> 4) + (n >> 4)) * 64 + lane) * 8 + (k & 7);
  hi[dst] = hs;
  lo[dst] = ls;
}

// ---------- MFMA split-bf16 GEMM v3: direct global->register A fragments -----
// No LDS, no barriers. Each wave owns a 16-row x 128-col strip.
// A-frag for 16x16x32: lane(ln15,quad) holds A[row=ln15][k=quad*8+j] — 8
// contiguous fp32 per lane; a wave's load covers 16 rows x 128 B (full lines).
// Split to bf16 hi/lo in registers; 3 MFMAs per tile (lo*hi + hi*lo + hi*hi).
template <class Pro, class Epi>
__global__ __launch_bounds__(256) void gemm_direct(
    const float* __restrict__ A,
    const unsigned short* __restrict__ Bhi, const unsigned short* __restrict__ Blo,
    float* __restrict__ C, int M, int N, int K, Pro pro, Epi epi) {
  const int tid = threadIdx.x;
  const int lane = tid & 63;
  const int wv = tid >> 6;
  const int quad = lane >> 4;
  const int ln15 = lane & 15;
  const int mrow0 = blockIdx.x * 64 + wv * 16;  // this wave's 16-row strip
  const int arow = mrow0 + ln15;                // row this lane loads for A
  const int col0 = blockIdx.y * 128;
  const int Nt = N >> 4;
  const int ntbase = col0 >> 4;
  const bool aok = (arow < M);
  const int KB = K >> 5;

  f32x4 acc[8] = {};

  for (int kb = 0; kb < KB; kb++) {
    // A fragment: 8 fp32 at row arow, cols kb*32 + quad*8
    float4 a0 = make_float4(0.f, 0.f, 0.f, 0.f), a1 = a0;
    if (aok) {
      const float* ap = A + (size_t)arow * K + kb * 32 + quad * 8;
      a0 = *(const float4*)ap;
      a1 = *(const float4*)(ap + 4);
      int cb = kb * 32 + quad * 8;
      a0.x = pro(a0.x, arow, cb + 0); a0.y = pro(a0.y, arow, cb + 1);
      a0.z = pro(a0.z, arow, cb + 2); a0.w = pro(a0.w, arow, cb + 3);
      a1.x = pro(a1.x, arow, cb + 4); a1.y = pro(a1.y, arow, cb + 5);
      a1.z = pro(a1.z, arow, cb + 6); a1.w = pro(a1.w, arow, cb + 7);
    }
    // split to bf16 hi/lo (truncation; lo compensates exactly)
    float f[8] = {a0.x, a0.y, a0.z, a0.w, a1.x, a1.y, a1.z, a1.w};
    union { unsigned u[4]; short8 v; } ch, cl;
#pragma unroll
    for (int e = 0; e < 4; e++) {
      unsigned u0 = __float_as_uint(f[2 * e]);
      unsigned u1 = __float_as_uint(f[2 * e + 1]);
      ch.u[e] = (u0 >> 16) | (u1 & 0xFFFF0000u);
      float h0 = __uint_as_float(u0 & 0xFFFF0000u);
      float h1 = __uint_as_float(u1 & 0xFFFF0000u);
      cl.u[e] = (__float_as_uint(f[2 * e] - h0) >> 16) |
                (__float_as_uint(f[2 * e + 1] - h1) & 0xFFFF0000u);
    }
    short8 ahi = ch.v, alo = cl.v;

    const unsigned short* bph = Bhi + ((size_t)(kb * Nt + ntbase) * 64 + lane) * 8;
    const unsigned short* bpl = Blo + ((size_t)(kb * Nt + ntbase) * 64 + lane) * 8;
#pragma unroll
    for (int nt = 0; nt < 8; nt++) {
      short8 bhi = *(const short8*)(bph + nt * 512);
      short8 blo = *(const short8*)(bpl + nt * 512);
      acc[nt] = __builtin_amdgcn_mfma_f32_16x16x32_bf16(alo, bhi, acc[nt], 0, 0, 0);
      acc[nt] = __builtin_amdgcn_mfma_f32_16x16x32_bf16(ahi, blo, acc[nt], 0, 0, 0);
      acc[nt] = __builtin_amdgcn_mfma_f32_16x16x32_bf16(ahi, bhi, acc[nt], 0, 0, 0);
    }
  }

  // epilogue: D[row = quad*4+r][col = ln15] per 16x16 tile
#pragma unroll
  for (int nt = 0; nt < 8; nt++) {
    f32x4 a = acc[nt];
    int gc = col0 + nt * 16 + ln15;
#pragma unroll
    for (int r = 0; r < 4; r++) {
      int gr = mrow0 + quad * 4 + r;
      if (gr < M) C[(size_t)gr * N + gc] = epi(a[r], gr, gc);
    }
  }
}

// ---------- LN + modulate: shsc rows = [sh(128)|sc(128)], stride 256 ----------
__global__ __launch_bounds__(256) void ln_mod_kernel(
    const float* __restrict__ x, const float* __restrict__ shsc,
    float* __restrict__ out) {
  int wave = threadIdx.x >> 6;
  int lane = threadIdx.x & 63;
  int row = blockIdx.x * 4 + wave;
  if (row >= N_NODES) return;
  float2 v = *(const float2*)(x + (size_t)row * HIDD + lane * 2);
  float s = v.x + v.y;
  float sq = v.x * v.x + v.y * v.y;
#pragma unroll
  for (int o = 32; o >= 1; o >>= 1) {
    s += __shfl_xor(s, o);
    sq += __shfl_xor(sq, o);
  }
  float m = s * (1.f / 128.f);
  float var = sq * (1.f / 128.f) - m * m;
  float rs = rsqrtf(var + 1e-6f);
  float2 sh = *(const float2*)(shsc + (size_t)row * 256 + lane * 2);
  float2 sc = *(const float2*)(shsc + (size_t)row * 256 + 128 + lane * 2);
  float2 o;
  o.x = (v.x - m) * rs * (1.f + sc.x) + sh.x;
  o.y = (v.y - m) * rs * (1.f + sc.y) + sh.y;
  *(float2*)(out + (size_t)row * HIDD + lane * 2) = o;
}

// ---------- CSR build ----------
__global__ __launch_bounds__(256) void zero_int_kernel(int* p, int n) {
  int i = blockIdx.x * 256 + threadIdx.x;
  if (i < n) p[i] = 0;
}

__global__ __launch_bounds__(256) void hist_kernel(const void* __restrict__ ei,
                                                   const int* __restrict__ flag,
                                                   int* __restrict__ A) {
  int e = blockIdx.x * 256 + threadIdx.x;
  if (e >= NE) return;
  int dst = load_idx(ei, *flag, (long long)NE + e);
  atomicAdd(&A[dst + 1], 1);
}

// 3-phase scan
__global__ __launch_bounds__(1024) void scan1_kernel(int* __restrict__ A, int n,
                                                     int* __restrict__ bsum) {
  __shared__ int buf[2][1024];
  int i = blockIdx.x * 1024 + threadIdx.x;
  int val = (i < n) ? A[i] : 0;
  int pb = 0;
  buf[0][threadIdx.x] = val;
  __syncthreads();
#pragma unroll
  for (int off = 1; off < 1024; off <<= 1) {
    int t = buf[pb][threadIdx.x];
    if ((int)threadIdx.x >= off) t += buf[pb][threadIdx.x - off];
    buf[pb ^ 1][threadIdx.x] = t;
    pb ^= 1;
    __syncthreads();
  }
  int incl = buf[pb][threadIdx.x];
  if (i < n) A[i] = incl;
  if (threadIdx.x == 1023) bsum[blockIdx.x] = incl;
}
__global__ void scan2_kernel(int* __restrict__ bsum, int nb) {
  int l = threadIdx.x;  // 64 threads, nb <= 64
  int v = (l < nb) ? bsum[l] : 0;
#pragma unroll
  for (int off = 1; off < 64; off <<= 1) {
    int t = __shfl_up(v, off);
    if (l >= off) v += t;
  }
  if (l < nb) bsum[l] = v;
}
__global__ __launch_bounds__(256) void scan3_kernel(int* __restrict__ A, int n,
                                                    const int* __restrict__ bsum) {
  int i = blockIdx.x * 256 + threadIdx.x;
  int b = i >> 10;
  if (i < n && b > 0) A[i] += bsum[b - 1];
}

// scatter: pos = A[dst]++, col[pos] = src. Afterwards A[i] == orig rowptr[i+1].
__global__ __launch_bounds__(256) void scatter_kernel(const void* __restrict__ ei,
                                                      const int* __restrict__ flag,
                                                      int* __restrict__ A,
                                                      unsigned short* __restrict__ col) {
  int e = blockIdx.x * 256 + threadIdx.x;
  if (e >= NE) return;
  int is64 = *flag;
  int src = load_idx(ei, is64, e);
  int dst = load_idx(ei, is64, (long long)NE + e);
  int pos = atomicAdd(&A[dst], 1);
  col[pos] = (unsigned short)src;
}

// ---------- fused per-node attention, v2: 2 edges/iter, max-free softmax -----
// qkv rows = [q(128)|k(128)|v(128)] stride 384, h-major.
// Wave layout: lanes 0-31 process even edges, lanes 32-63 odd edges.
// Each lane owns 4 contiguous dims (float4) => head = l32>>2; dot-reduce is
// 2 shfl_xor over the 4-lane group. Softmax is max-free: scores are
// (q.k)/4 with sigma~2 over LN'd inputs, max ~12 << 88 (f32 exp overflow);
// w = exp(min(s,60)) is exact after normalization (offset cancels in ratio).
// Final cross-half combine: one shfl_xor(32) per accumulator per node.
__global__ __launch_bounds__(256) void node_attn_kernel(
    const int* __restrict__ A, const unsigned short* __restrict__ col,
    const float* __restrict__ qkv, float* __restrict__ attn) {
  int wave = threadIdx.x >> 6;
  int lane = threadIdx.x & 63;
  int half = lane >> 5;   // 0: even edges, 1: odd edges
  int l32 = lane & 31;    // dims l32*4 .. l32*4+3
  int node = blockIdx.x * 4 + wave;
  if (node >= N_NODES) return;
  int start = (node == 0) ? 0 : A[node - 1];
  int end = A[node];
  int deg = end - start;

  float4 q = *(const float4*)(qkv + (size_t)node * 384 + l32 * 4);
  float l = 0.f;
  float4 acc = make_float4(0.f, 0.f, 0.f, 0.f);

  if (deg > 0) {
    int itc = (deg + 1) >> 1;
    int last = end - 1;
    int e0 = min(start + half, last);
    int i0 = col[e0];
    float4 kc = *(const float4*)(qkv + (size_t)i0 * 384 + 128 + l32 * 4);
    float4 vc = *(const float4*)(qkv + (size_t)i0 * 384 + 256 + l32 * 4);
    for (int it = 0; it < itc; it++) {
      float4 kn = kc, vn = vc;
      if (it + 1 < itc) {
        int e1 = min(start + 2 * (it + 1) + half, last);
        int i1 = col[e1];
        kn = *(const float4*)(qkv + (size_t)i1 * 384 + 128 + l32 * 4);
        vn = *(const float4*)(qkv + (size_t)i1 * 384 + 256 + l32 * 4);
      }
      float s = q.x * kc.x + q.y * kc.y + q.z * kc.z + q.w * kc.w;
      s += __shfl_xor(s, 1);
      s += __shfl_xor(s, 2);
      s *= 0.25f;  // 1/sqrt(16)
      bool valid = (start + 2 * it + half) < end;
      float w = valid ? __expf(fminf(s, 60.f)) : 0.f;
      l += w;
      acc.x += w * vc.x;
      acc.y += w * vc.y;
      acc.z += w * vc.z;
      acc.w += w * vc.w;
      kc = kn;
      vc = vn;
    }
  }
  // combine even/odd halves (both halves end with the full sums)
  l += __shfl_xor(l, 32);
  acc.x += __shfl_xor(acc.x, 32);
  acc.y += __shfl_xor(acc.y, 32);
  acc.z += __shfl_xor(acc.z, 32);
  acc.w += __shfl_xor(acc.w, 32);
  float inv = (l > 0.f) ? 1.f / l : 0.f;
  if (half == 0) {
    float4 o = make_float4(acc.x * inv, acc.y * inv, acc.z * inv, acc.w * inv);
    *(float4*)(attn + (size_t)node * HIDD + l32 * 4) = o;
  }
}

extern "C" void kernel_launch(void* const* d_in, const int* in_sizes, int n_in,
                              void* d_out, int out_size, void* d_ws, size_t ws_size,
                              hipStream_t stream) {
  const float* x      = (const float*)d_in[0];
  const void*  ei     = d_in[1];
  const float* c      = (const float*)d_in[2];
  const float* w_qkv  = (const float*)d_in[3];
  const float* w_proj = (const float*)d_in[4];
  const float* b_proj = (const float*)d_in[5];
  const float* w_mlp1 = (const float*)d_in[6];
  const float* b_mlp1 = (const float*)d_in[7];
  const float* w_mlp2 = (const float*)d_in[8];
  const float* b_mlp2 = (const float*)d_in[9];
  const float* w_ada  = (const float*)d_in[10];
  const float* b_ada  = (const float*)d_in[11];
  float* out = (float*)d_out;

  // ---- pool layout (floats): xm(128) | P1(256) | P3(384) + CSR + B planes ---
  const size_t NM = (size_t)N_NODES;
  float* pool = (float*)d_ws;
  float* xm    = pool;                       // N*128: LN out; attn overlay
  float* P1    = xm + NM * 128;              // N*256: ada shsc chunks; gmsa; h1 part
  float* P3    = P1 + NM * 256;              // N*384: qkv; h1 part; gmlp tail
  int*   Arow  = (int*)(P3 + NM * 384);      // 50048 ints
  unsigned short* col = (unsigned short*)(Arow + 50048);  // E ushort
  int*   eflag = (int*)(col + NE);           // 8 ints
  int*   bsum  = eflag + 8;                  // 64 ints
  unsigned short* Bhi = (unsigned short*)(bsum + 64);  // 294912
  unsigned short* Blo = Bhi + 294912;                  // 294912
  // overlays
  float* attn  = xm;                         // after qkv GEMM, xm dead
  float* gmsa  = P1;                         // [N,128] after ln1
  float* h1    = P1;                         // N*512 spans P1 + P3[:,0:256]
  float* gmlp  = P3 + NM * 256;              // [N,128] tail of P3

  // B-plane element offsets
  const int o_qkv = 0, o_ada0 = 49152, o_gmsa = 81920, o_adam = 98304,
            o_gmlp = 131072, o_proj = 147456, o_mlp1 = 163840, o_mlp2 = 229376;
  const int cv_total = 294912;

  const size_t req_bytes = (NM * 768) * 4 + 50048 * 4 + NE * 2 + 32 + 256 +
                           (size_t)cv_total * 2 * 2;
  dim3 blk(256);
  if (ws_size < req_bytes) {
    probe_kernel<<<dim3((out_size + 255) / 256), blk, 0, stream>>>(
        out, out_size, (float)(ws_size >> 20));
    return;
  }

  const int MB = (N_NODES + 63) / 64;   // 782 row-blocks (64 rows, 4 waves)
  const int EB = (NE + 255) / 256;
  const int SB = (N_NODES + 1 + 1023) / 1024;  // 49 scan blocks

  // 0. dtype detect + CSR build
  detect_kernel<<<dim3(1), blk, 0, stream>>>((const unsigned*)ei, eflag);
  zero_int_kernel<<<dim3((N_NODES + 1 + 255) / 256), blk, 0, stream>>>(Arow, N_NODES + 1);
  hist_kernel<<<dim3(EB), blk, 0, stream>>>(ei, eflag, Arow);
  scan1_kernel<<<dim3(SB), dim3(1024), 0, stream>>>(Arow, N_NODES + 1, bsum);
  scan2_kernel<<<dim3(1), dim3(64), 0, stream>>>(bsum, SB);
  scan3_kernel<<<dim3((N_NODES + 1 + 255) / 256), blk, 0, stream>>>(Arow, N_NODES + 1, bsum);
  scatter_kernel<<<dim3(EB), blk, 0, stream>>>(ei, eflag, Arow, col);

  // 0b. pre-split all weights into fragment-ordered bf16 hi/lo planes (1 launch)
  {
    CvTab t;
    // seg:            qkv     ada0    gmsa    adam    gmlp    proj    mlp1    mlp2
    int sel[8]     = { 0,      1,      1,      1,      1,      2,      3,      4 };
    int soff[8]    = { 0,      0,      256,    384,    640,    0,      0,      0 };
    int ldb[8]     = { 384,    768,    768,    768,    768,    128,    512,    128 };
    int nn[8]      = { 384,    256,    128,    256,    128,    128,    512,    128 };
    int doff[8]    = { o_qkv,  o_ada0, o_gmsa, o_adam, o_gmlp, o_proj, o_mlp1, o_mlp2 };
    int cnt[8]     = { 49152,  32768,  16384,  32768,  16384,  16384,  65536,  65536 };
    int accum = 0;
    for (int s = 0; s < 8; s++) {
      accum += cnt[s];
      t.end[s] = accum; t.src_sel[s] = sel[s]; t.src_off[s] = soff[s];
      t.ldb[s] = ldb[s]; t.n[s] = nn[s]; t.dst_off[s] = doff[s];
    }
    convert_all_kernel<<<dim3((cv_total + 255) / 256), blk, 0, stream>>>(
        w_qkv, w_ada, w_proj, w_mlp1, w_mlp2, t, cv_total, Bhi, Blo);
  }

  // 1. P1 = silu(c) @ w_ada[:,0:256] + b  (sh_msa|sc_msa)
  gemm_direct<ProSilu, EpiBias><<<dim3(MB, 2), blk, 0, stream>>>(
      c, Bhi + o_ada0, Blo + o_ada0, P1, N_NODES, 256, 128, ProSilu{}, EpiBias{b_ada});

  // 2. xm = modulate(ln(x), sh_msa, sc_msa)
  ln_mod_kernel<<<dim3((N_NODES + 3) / 4), blk, 0, stream>>>(x, P1, xm);

  // 3. P3 = xm @ w_qkv  [N,384] = q|k|v
  gemm_direct<ProNone, EpiNone><<<dim3(MB, 3), blk, 0, stream>>>(
      xm, Bhi + o_qkv, Blo + o_qkv, P3, N_NODES, 384, 128, ProNone{}, EpiNone{});

  // 4. fused graph attention -> attn (overlays xm; xm dead after step 3)
  node_attn_kernel<<<dim3((N_NODES + 3) / 4), blk, 0, stream>>>(Arow, col, P3, attn);

  // 5. gmsa = silu(c) @ w_ada[:,256:384] + b  (P1 shsc dead after ln1)
  gemm_direct<ProSilu, EpiBias><<<dim3(MB, 1), blk, 0, stream>>>(
      c, Bhi + o_gmsa, Blo + o_gmsa, gmsa, N_NODES, 128, 128, ProSilu{}, EpiBias{b_ada + 256});

  // 6. x1(d_out) = x + gmsa * (attn @ w_proj + b_proj)
  gemm_direct<ProNone, EpiResGate><<<dim3(MB, 1), blk, 0, stream>>>(
      attn, Bhi + o_proj, Blo + o_proj, out, N_NODES, 128, 128, ProNone{},
      EpiResGate{b_proj, x, gmsa});

  // 7. P1 = silu(c) @ w_ada[:,384:640] + b  (sh_mlp|sc_mlp; gmsa dead)
  gemm_direct<ProSilu, EpiBias><<<dim3(MB, 2), blk, 0, stream>>>(
      c, Bhi + o_adam, Blo + o_adam, P1, N_NODES, 256, 128, ProSilu{}, EpiBias{b_ada + 384});

  // 8. xm = modulate(ln(x1), sh_mlp, sc_mlp)  (attn dead after step 6)
  ln_mod_kernel<<<dim3((N_NODES + 3) / 4), blk, 0, stream>>>(out, P1, xm);

  // 9. gmlp = silu(c) @ w_ada[:,640:768] + b  -> P3 tail (qkv dead after attn)
  gemm_direct<ProSilu, EpiBias><<<dim3(MB, 1), blk, 0, stream>>>(
      c, Bhi + o_gmlp, Blo + o_gmlp, gmlp, N_NODES, 128, 128, ProSilu{}, EpiBias{b_ada + 640});

  // 10. h1 = gelu(xm @ w_mlp1 + b_mlp1)  [N,512] over P1 + P3[:,0:256]
  gemm_direct<ProNone, EpiGelu><<<dim3(MB, 4), blk, 0, stream>>>(
      xm, Bhi + o_mlp1, Blo + o_mlp1, h1, N_NODES, 512, 128, ProNone{}, EpiGelu{b_mlp1});

  // 11. out = x1 + gmlp * (h1 @ w_mlp2 + b_mlp2)  (in-place: safe)
  gemm_direct<ProNone, EpiResGate><<<dim3(MB, 1), blk, 0, stream>>>(
      h1, Bhi + o_mlp2, Blo + o_mlp2, out, N_NODES, 128, 512, ProNone{},
      EpiResGate{b_mlp2, out, gmlp});
}

// Round 2
// 592.031 us; speedup vs baseline: 1.0772x; 1.0740x over previous
//
#include <hip/hip_runtime.h>
#include <math.h>

#define N_NODES 50000
#define HIDD 128
#define HEADS 8
#define HDIM 16
#define NE 800000

using short8 = __attribute__((ext_vector_type(8))) short;
using f32x4 = __attribute__((ext_vector_type(4))) float;

// ---------- dtype-robust edge-index load (clamped: can never fault) ----------
__device__ __forceinline__ int load_idx(const void* ei, int is64, long long pos) {
  long long v = is64 ? ((const long long*)ei)[pos]
                     : (long long)((const int*)ei)[pos];
  unsigned uv = (unsigned)v;
  return (uv < N_NODES) ? (int)uv : 0;
}

// int64 vs int32 detect: LE int64 < 2^31 has every odd int32 word == 0.
__global__ void detect_kernel(const unsigned* __restrict__ ei_raw, int* flag) {
  __shared__ int any_nonzero;
  if (threadIdx.x == 0) any_nonzero = 0;
  __syncthreads();
  if (threadIdx.x < 128) {
    if (ei_raw[2 * threadIdx.x + 1] != 0u) atomicOr(&any_nonzero, 1);
  }
  __syncthreads();
  if (threadIdx.x == 0) *flag = any_nonzero ? 0 : 1;  // 1 => int64
}

// ---------- ws-too-small probe: absmax ~= ws_size in MB ----------
__global__ __launch_bounds__(256) void probe_kernel(float* out, int n, float mb) {
  int i = blockIdx.x * 256 + threadIdx.x;
  if (i < n) out[i] = (i == 0) ? mb : 0.f;
}

// ---------- prologue / epilogue functors ----------
struct ProNone {
  __device__ __forceinline__ float operator()(float v, int, int) const { return v; }
};
struct ProSilu {
  __device__ __forceinline__ float operator()(float v, int, int) const {
    return v / (1.f + __expf(-v));
  }
};
struct EpiNone {
  __device__ __forceinline__ float operator()(float a, int, int) const { return a; }
};
struct EpiBias {
  const float* b;  // pre-offset on host
  __device__ __forceinline__ float operator()(float a, int, int c) const { return a + b[c]; }
};
struct EpiGelu {
  const float* b;
  __device__ __forceinline__ float operator()(float a, int, int c) const {
    float t = a + b[c];
    float u = 0.7978845608028654f * (t + 0.044715f * t * t * t);
    return 0.5f * t * (1.f + tanhf(u));
  }
};
struct EpiResGate {  // xres[r,c] + gate[r,c] * (a + b[c]); gate/xres stride 128
  const float* b;
  const float* xres;
  const float* gate;
  __device__ __forceinline__ float operator()(float a, int r, int c) const {
    return xres[(size_t)r * HIDD + c] + gate[(size_t)r * HIDD + c] * (a + b[c]);
  }
};

// ---------- fused B pre-split: 8 segments, fragment-ordered bf16 hi/lo -------
// Element B[k][n] of segment s lands at:
//   lane = ((k>>3)&3)*16 + (n&15), j = k&7
//   dst  = dst_off + (((k>>5)*(N/16) + (n>>4))*64 + lane)*8 + j
struct CvTab {
  int end[8];
  int src_sel[8];
  int src_off[8];
  int ldb[8];
  int n[8];
  int dst_off[8];
};
__global__ __launch_bounds__(256) void convert_all_kernel(
    const float* __restrict__ p0, const float* __restrict__ p1,
    const float* __restrict__ p2, const float* __restrict__ p3,
    const float* __restrict__ p4, CvTab t, int total,
    unsigned short* __restrict__ hi, unsigned short* __restrict__ lo) {
  int idx = blockIdx.x * 256 + threadIdx.x;
  if (idx >= total) return;
  int s = 0;
#pragma unroll
  for (int j = 0; j < 7; j++) s += (idx >= t.end[j]) ? 1 : 0;
  int local = idx - (s ? t.end[s - 1] : 0);
  int N = t.n[s];
  int k = (unsigned)local / (unsigned)N;
  int n = local - k * N;
  const float* B;
  int sel = t.src_sel[s];
  B = (sel == 0) ? p0 : (sel == 1) ? p1 : (sel == 2) ? p2 : (sel == 3) ? p3 : p4;
  float f = B[(size_t)k * t.ldb[s] + t.src_off[s] + n];
  unsigned u = __float_as_uint(f);
  unsigned short hs = (unsigned short)(u >> 16);  // truncated bf16 hi
  float hf = __uint_as_float(u & 0xFFFF0000u);
  unsigned short ls = (unsigned short)(__float_as_uint(f - hf) >> 16);
  int lane = (((k >> 3) & 3) << 4) | (n & 15);
  int dst = t.dst_off[s] + (((k >> 5) * (N >> 4) + (n >> 4)) * 64 + lane) * 8 + (k & 7);
  hi[dst] = hs;
  lo[dst] = ls;
}

// ---------- MFMA split-bf16 GEMM v3: direct global->register A fragments -----
// No LDS, no barriers. Each wave owns a 16-row x 128-col strip.
// A-frag for 16x16x32: lane(ln15,quad) holds A[row=ln15][k=quad*8+j] — 8
// contiguous fp32 per lane; a wave's load covers 16 rows x 128 B (full lines).
// Split to bf16 hi/lo in registers; 3 MFMAs per tile (lo*hi + hi*lo + hi*hi).
// QKV mode: cols [0,128) stored f32; cols [128,384) stored bf16(RNE) packed at
// ushort index 128+gc of the row (row = q[128 f32] | k[128 bf16] | v[128 bf16]).
template <class Pro, class Epi, bool QKV = false>
__global__ __launch_bounds__(256) void gemm_direct(
    const float* __restrict__ A,
    const unsigned short* __restrict__ Bhi, const unsigned short* __restrict__ Blo,
    float* __restrict__ C, int M, int N, int K, Pro pro, Epi epi) {
  const int tid = threadIdx.x;
  const int lane = tid & 63;
  const int wv = tid >> 6;
  const int quad = lane >> 4;
  const int ln15 = lane & 15;
  const int mrow0 = blockIdx.x * 64 + wv * 16;  // this wave's 16-row strip
  const int arow = mrow0 + ln15;                // row this lane loads for A
  const int col0 = blockIdx.y * 128;
  const int Nt = N >> 4;
  const int ntbase = col0 >> 4;
  const bool aok = (arow < M);
  const int KB = K >> 5;

  f32x4 acc[8] = {};

  for (int kb = 0; kb < KB; kb++) {
    // A fragment: 8 fp32 at row arow, cols kb*32 + quad*8
    float4 a0 = make_float4(0.f, 0.f, 0.f, 0.f), a1 = a0;
    if (aok) {
      const float* ap = A + (size_t)arow * K + kb * 32 + quad * 8;
      a0 = *(const float4*)ap;
      a1 = *(const float4*)(ap + 4);
      int cb = kb * 32 + quad * 8;
      a0.x = pro(a0.x, arow, cb + 0); a0.y = pro(a0.y, arow, cb + 1);
      a0.z = pro(a0.z, arow, cb + 2); a0.w = pro(a0.w, arow, cb + 3);
      a1.x = pro(a1.x, arow, cb + 4); a1.y = pro(a1.y, arow, cb + 5);
      a1.z = pro(a1.z, arow, cb + 6); a1.w = pro(a1.w, arow, cb + 7);
    }
    // split to bf16 hi/lo (truncation; lo compensates exactly)
    float f[8] = {a0.x, a0.y, a0.z, a0.w, a1.x, a1.y, a1.z, a1.w};
    union { unsigned u[4]; short8 v; } ch, cl;
#pragma unroll
    for (int e = 0; e < 4; e++) {
      unsigned u0 = __float_as_uint(f[2 * e]);
      unsigned u1 = __float_as_uint(f[2 * e + 1]);
      ch.u[e] = (u0 >> 16) | (u1 & 0xFFFF0000u);
      float h0 = __uint_as_float(u0 & 0xFFFF0000u);
      float h1 = __uint_as_float(u1 & 0xFFFF0000u);
      cl.u[e] = (__float_as_uint(f[2 * e] - h0) >> 16) |
                (__float_as_uint(f[2 * e + 1] - h1) & 0xFFFF0000u);
    }
    short8 ahi = ch.v, alo = cl.v;

    const unsigned short* bph = Bhi + ((size_t)(kb * Nt + ntbase) * 64 + lane) * 8;
    const unsigned short* bpl = Blo + ((size_t)(kb * Nt + ntbase) * 64 + lane) * 8;
#pragma unroll
    for (int nt = 0; nt < 8; nt++) {
      short8 bhi = *(const short8*)(bph + nt * 512);
      short8 blo = *(const short8*)(bpl + nt * 512);
      acc[nt] = __builtin_amdgcn_mfma_f32_16x16x32_bf16(alo, bhi, acc[nt], 0, 0, 0);
      acc[nt] = __builtin_amdgcn_mfma_f32_16x16x32_bf16(ahi, blo, acc[nt], 0, 0, 0);
      acc[nt] = __builtin_amdgcn_mfma_f32_16x16x32_bf16(ahi, bhi, acc[nt], 0, 0, 0);
    }
  }

  // epilogue: D[row = quad*4+r][col = ln15] per 16x16 tile
#pragma unroll
  for (int nt = 0; nt < 8; nt++) {
    f32x4 a = acc[nt];
    int gc = col0 + nt * 16 + ln15;
#pragma unroll
    for (int r = 0; r < 4; r++) {
      int gr = mrow0 + quad * 4 + r;
      if (gr < M) {
        if constexpr (QKV) {
          if (gc < 128) {
            C[(size_t)gr * N + gc] = a[r];
          } else {
            unsigned u = __float_as_uint(a[r]);
            unsigned rr = (u + 0x7FFFu + ((u >> 16) & 1u)) >> 16;  // RNE bf16
            ((unsigned short*)(C + (size_t)gr * N))[128 + gc] = (unsigned short)rr;
          }
        } else {
          C[(size_t)gr * N + gc] = epi(a[r], gr, gc);
        }
      }
    }
  }
}

// ---------- LN + modulate: shsc rows = [sh(128)|sc(128)], stride 256 ----------
__global__ __launch_bounds__(256) void ln_mod_kernel(
    const float* __restrict__ x, const float* __restrict__ shsc,
    float* __restrict__ out) {
  int wave = threadIdx.x >> 6;
  int lane = threadIdx.x & 63;
  int row = blockIdx.x * 4 + wave;
  if (row >= N_NODES) return;
  float2 v = *(const float2*)(x + (size_t)row * HIDD + lane * 2);
  float s = v.x + v.y;
  float sq = v.x * v.x + v.y * v.y;
#pragma unroll
  for (int o = 32; o >= 1; o >>= 1) {
    s += __shfl_xor(s, o);
    sq += __shfl_xor(sq, o);
  }
  float m = s * (1.f / 128.f);
  float var = sq * (1.f / 128.f) - m * m;
  float rs = rsqrtf(var + 1e-6f);
  float2 sh = *(const float2*)(shsc + (size_t)row * 256 + lane * 2);
  float2 sc = *(const float2*)(shsc + (size_t)row * 256 + 128 + lane * 2);
  float2 o;
  o.x = (v.x - m) * rs * (1.f + sc.x) + sh.x;
  o.y = (v.y - m) * rs * (1.f + sc.y) + sh.y;
  *(float2*)(out + (size_t)row * HIDD + lane * 2) = o;
}

// ---------- CSR build ----------
__global__ __launch_bounds__(256) void zero_int_kernel(int* p, int n) {
  int i = blockIdx.x * 256 + threadIdx.x;
  if (i < n) p[i] = 0;
}

__global__ __launch_bounds__(256) void hist_kernel(const void* __restrict__ ei,
                                                   const int* __restrict__ flag,
                                                   int* __restrict__ A) {
  int e = blockIdx.x * 256 + threadIdx.x;
  if (e >= NE) return;
  int dst = load_idx(ei, *flag, (long long)NE + e);
  atomicAdd(&A[dst + 1], 1);
}

// 3-phase scan
__global__ __launch_bounds__(1024) void scan1_kernel(int* __restrict__ A, int n,
                                                     int* __restrict__ bsum) {
  __shared__ int buf[2][1024];
  int i = blockIdx.x * 1024 + threadIdx.x;
  int val = (i < n) ? A[i] : 0;
  int pb = 0;
  buf[0][threadIdx.x] = val;
  __syncthreads();
#pragma unroll
  for (int off = 1; off < 1024; off <<= 1) {
    int t = buf[pb][threadIdx.x];
    if ((int)threadIdx.x >= off) t += buf[pb][threadIdx.x - off];
    buf[pb ^ 1][threadIdx.x] = t;
    pb ^= 1;
    __syncthreads();
  }
  int incl = buf[pb][threadIdx.x];
  if (i < n) A[i] = incl;
  if (threadIdx.x == 1023) bsum[blockIdx.x] = incl;
}
__global__ void scan2_kernel(int* __restrict__ bsum, int nb) {
  int l = threadIdx.x;  // 64 threads, nb <= 64
  int v = (l < nb) ? bsum[l] : 0;
#pragma unroll
  for (int off = 1; off < 64; off <<= 1) {
    int t = __shfl_up(v, off);
    if (l >= off) v += t;
  }
  if (l < nb) bsum[l] = v;
}
__global__ __launch_bounds__(256) void scan3_kernel(int* __restrict__ A, int n,
                                                    const int* __restrict__ bsum) {
  int i = blockIdx.x * 256 + threadIdx.x;
  int b = i >> 10;
  if (i < n && b > 0) A[i] += bsum[b - 1];
}

// scatter: pos = A[dst]++, col[pos] = src. Afterwards A[i] == orig rowptr[i+1].
__global__ __launch_bounds__(256) void scatter_kernel(const void* __restrict__ ei,
                                                      const int* __restrict__ flag,
                                                      int* __restrict__ A,
                                                      unsigned short* __restrict__ col) {
  int e = blockIdx.x * 256 + threadIdx.x;
  if (e >= NE) return;
  int is64 = *flag;
  int src = load_idx(ei, is64, e);
  int dst = load_idx(ei, is64, (long long)NE + e);
  int pos = atomicAdd(&A[dst], 1);
  col[pos] = (unsigned short)src;
}

// ---------- fused per-node attention, v3: bf16 k/v gather, 2 edges/iter ------
// qkv rows (1536B): q[128 f32] | k[128 bf16] | v[128 bf16] | 512B unused.
// Wave layout: lanes 0-31 even edges, lanes 32-63 odd edges; each lane owns 4
// contiguous dims (head = l32>>2); dot-reduce = 2 shfl_xor over 4-lane group.
// Max-free softmax: s = (q.k)/4, |s| << 88 for LN'd inputs; w = exp(min(s,60))
// is exact after normalization. Index prefetch decoupled 2 iters ahead so no
// serial col->gather chain. Gather: 256B/row (half of fp32) — the kernel was
// proven L2-fill-traffic-bound (r1: VALU cut, dur unchanged, FETCH identical).
__global__ __launch_bounds__(256) void node_attn_kernel(
    const int* __restrict__ A, const unsigned short* __restrict__ col,
    const float* __restrict__ qkv, float* __restrict__ attn) {
  int wave = threadIdx.x >> 6;
  int lane = threadIdx.x & 63;
  int half = lane >> 5;   // 0: even edges, 1: odd edges
  int l32 = lane & 31;    // dims l32*4 .. l32*4+3
  int node = blockIdx.x * 4 + wave;
  if (node >= N_NODES) return;
  int start = (node == 0) ? 0 : A[node - 1];
  int end = A[node];
  int deg = end - start;

  float4 q = *(const float4*)(qkv + (size_t)node * 384 + l32 * 4);
  float l = 0.f;
  float4 acc = make_float4(0.f, 0.f, 0.f, 0.f);

  if (deg > 0) {
    int itc = (deg + 1) >> 1;
    int last = end - 1;
    const unsigned* qu = (const unsigned*)qkv;
    // edge index for iteration it (clamped; clamped dups get w=0 via valid mask)
    auto eidx = [&](int it) {
      int e = start + 2 * it + half;
      return (e <= last) ? e : last;
    };
    int i_cur = col[eidx(0)];
    int i_nxt = col[eidx(1)];  // clamped-safe even when itc==1
    // k at uint idx 128+2*l32, v at 192+2*l32 within the 384-uint row
    uint2 kcw = *(const uint2*)(qu + (size_t)i_cur * 384 + 128 + 2 * l32);
    uint2 vcw = *(const uint2*)(qu + (size_t)i_cur * 384 + 192 + 2 * l32);
    for (int it = 0; it < itc; it++) {
      uint2 knw = kcw, vnw = vcw;
      if (it + 1 < itc) {
        knw = *(const uint2*)(qu + (size_t)i_nxt * 384 + 128 + 2 * l32);
        vnw = *(const uint2*)(qu + (size_t)i_nxt * 384 + 192 + 2 * l32);
      }
      i_nxt = col[eidx(it + 2)];  // prefetch index 2 iters ahead (clamped-safe)
      float kx = __uint_as_float(kcw.x << 16);
      float ky = __uint_as_float(kcw.x & 0xFFFF0000u);
      float kz = __uint_as_float(kcw.y << 16);
      float kw = __uint_as_float(kcw.y & 0xFFFF0000u);
      float s = q.x * kx + q.y * ky + q.z * kz + q.w * kw;
      s += __shfl_xor(s, 1);
      s += __shfl_xor(s, 2);
      s *= 0.25f;  // 1/sqrt(16)
      bool valid = (start + 2 * it + half) < end;
      float w = valid ? __expf(fminf(s, 60.f)) : 0.f;
      float vx = __uint_as_float(vcw.x << 16);
      float vy = __uint_as_float(vcw.x & 0xFFFF0000u);
      float vz = __uint_as_float(vcw.y << 16);
      float vw = __uint_as_float(vcw.y & 0xFFFF0000u);
      l += w;
      acc.x += w * vx;
      acc.y += w * vy;
      acc.z += w * vz;
      acc.w += w * vw;
      kcw = knw;
      vcw = vnw;
    }
  }
  // combine even/odd halves (both halves end with the full sums)
  l += __shfl_xor(l, 32);
  acc.x += __shfl_xor(acc.x, 32);
  acc.y += __shfl_xor(acc.y, 32);
  acc.z += __shfl_xor(acc.z, 32);
  acc.w += __shfl_xor(acc.w, 32);
  float inv = (l > 0.f) ? 1.f / l : 0.f;
  if (half == 0) {
    float4 o = make_float4(acc.x * inv, acc.y * inv, acc.z * inv, acc.w * inv);
    *(float4*)(attn + (size_t)node * HIDD + l32 * 4) = o;
  }
}

extern "C" void kernel_launch(void* const* d_in, const int* in_sizes, int n_in,
                              void* d_out, int out_size, void* d_ws, size_t ws_size,
                              hipStream_t stream) {
  const float* x      = (const float*)d_in[0];
  const void*  ei     = d_in[1];
  const float* c      = (const float*)d_in[2];
  const float* w_qkv  = (const float*)d_in[3];
  const float* w_proj = (const float*)d_in[4];
  const float* b_proj = (const float*)d_in[5];
  const float* w_mlp1 = (const float*)d_in[6];
  const float* b_mlp1 = (const float*)d_in[7];
  const float* w_mlp2 = (const float*)d_in[8];
  const float* b_mlp2 = (const float*)d_in[9];
  const float* w_ada  = (const float*)d_in[10];
  const float* b_ada  = (const float*)d_in[11];
  float* out = (float*)d_out;

  // ---- pool layout (floats): xm(128) | P1(256) | P3(384) + CSR + B planes ---
  const size_t NM = (size_t)N_NODES;
  float* pool = (float*)d_ws;
  float* xm    = pool;                       // N*128: LN out; attn overlay
  float* P1    = xm + NM * 128;              // N*256: ada shsc chunks; gmsa; h1 part
  float* P3    = P1 + NM * 256;              // N*384: qkv; h1 part; gmlp tail
  int*   Arow  = (int*)(P3 + NM * 384);      // 50048 ints
  unsigned short* col = (unsigned short*)(Arow + 50048);  // E ushort
  int*   eflag = (int*)(col + NE);           // 8 ints
  int*   bsum  = eflag + 8;                  // 64 ints
  unsigned short* Bhi = (unsigned short*)(bsum + 64);  // 294912
  unsigned short* Blo = Bhi + 294912;                  // 294912
  // overlays
  float* attn  = xm;                         // after qkv GEMM, xm dead
  float* gmsa  = P1;                         // [N,128] after ln1
  float* h1    = P1;                         // N*512 spans P1 + P3[:,0:256]
  float* gmlp  = P3 + NM * 256;              // [N,128] tail of P3

  // B-plane element offsets
  const int o_qkv = 0, o_ada0 = 49152, o_gmsa = 81920, o_adam = 98304,
            o_gmlp = 131072, o_proj = 147456, o_mlp1 = 163840, o_mlp2 = 229376;
  const int cv_total = 294912;

  const size_t req_bytes = (NM * 768) * 4 + 50048 * 4 + NE * 2 + 32 + 256 +
                           (size_t)cv_total * 2 * 2;
  dim3 blk(256);
  if (ws_size < req_bytes) {
    probe_kernel<<<dim3((out_size + 255) / 256), blk, 0, stream>>>(
        out, out_size, (float)(ws_size >> 20));
    return;
  }

  const int MB = (N_NODES + 63) / 64;   // 782 row-blocks (64 rows, 4 waves)
  const int EB = (NE + 255) / 256;
  const int SB = (N_NODES + 1 + 1023) / 1024;  // 49 scan blocks

  // 0. dtype detect + CSR build
  detect_kernel<<<dim3(1), blk, 0, stream>>>((const unsigned*)ei, eflag);
  zero_int_kernel<<<dim3((N_NODES + 1 + 255) / 256), blk, 0, stream>>>(Arow, N_NODES + 1);
  hist_kernel<<<dim3(EB), blk, 0, stream>>>(ei, eflag, Arow);
  scan1_kernel<<<dim3(SB), dim3(1024), 0, stream>>>(Arow, N_NODES + 1, bsum);
  scan2_kernel<<<dim3(1), dim3(64), 0, stream>>>(bsum, SB);
  scan3_kernel<<<dim3((N_NODES + 1 + 255) / 256), blk, 0, stream>>>(Arow, N_NODES + 1, bsum);
  scatter_kernel<<<dim3(EB), blk, 0, stream>>>(ei, eflag, Arow, col);

  // 0b. pre-split all weights into fragment-ordered bf16 hi/lo planes (1 launch)
  {
    CvTab t;
    // seg:            qkv     ada0    gmsa    adam    gmlp    proj    mlp1    mlp2
    int sel[8]     = { 0,      1,      1,      1,      1,      2,      3,      4 };
    int soff[8]    = { 0,      0,      256,    384,    640,    0,      0,      0 };
    int ldb[8]     = { 384,    768,    768,    768,    768,    128,    512,    128 };
    int nn[8]      = { 384,    256,    128,    256,    128,    128,    512,    128 };
    int doff[8]    = { o_qkv,  o_ada0, o_gmsa, o_adam, o_gmlp, o_proj, o_mlp1, o_mlp2 };
    int cnt[8]     = { 49152,  32768,  16384,  32768,  16384,  16384,  65536,  65536 };
    int accum = 0;
    for (int s = 0; s < 8; s++) {
      accum += cnt[s];
      t.end[s] = accum; t.src_sel[s] = sel[s]; t.src_off[s] = soff[s];
      t.ldb[s] = ldb[s]; t.n[s] = nn[s]; t.dst_off[s] = doff[s];
    }
    convert_all_kernel<<<dim3((cv_total + 255) / 256), blk, 0, stream>>>(
        w_qkv, w_ada, w_proj, w_mlp1, w_mlp2, t, cv_total, Bhi, Blo);
  }

  // 1. P1 = silu(c) @ w_ada[:,0:256] + b  (sh_msa|sc_msa)
  gemm_direct<ProSilu, EpiBias><<<dim3(MB, 2), blk, 0, stream>>>(
      c, Bhi + o_ada0, Blo + o_ada0, P1, N_NODES, 256, 128, ProSilu{}, EpiBias{b_ada});

  // 2. xm = modulate(ln(x), sh_msa, sc_msa)
  ln_mod_kernel<<<dim3((N_NODES + 3) / 4), blk, 0, stream>>>(x, P1, xm);

  // 3. P3 = xm @ w_qkv  [N,384] = q(f32)|k(bf16)|v(bf16)
  gemm_direct<ProNone, EpiNone, true><<<dim3(MB, 3), blk, 0, stream>>>(
      xm, Bhi + o_qkv, Blo + o_qkv, P3, N_NODES, 384, 128, ProNone{}, EpiNone{});

  // 4. fused graph attention -> attn (overlays xm; xm dead after step 3)
  node_attn_kernel<<<dim3((N_NODES + 3) / 4), blk, 0, stream>>>(Arow, col, P3, attn);

  // 5. gmsa = silu(c) @ w_ada[:,256:384] + b  (P1 shsc dead after ln1)
  gemm_direct<ProSilu, EpiBias><<<dim3(MB, 1), blk, 0, stream>>>(
      c, Bhi + o_gmsa, Blo + o_gmsa, gmsa, N_NODES, 128, 128, ProSilu{}, EpiBias{b_ada + 256});

  // 6. x1(d_out) = x + gmsa * (attn @ w_proj + b_proj)
  gemm_direct<ProNone, EpiResGate><<<dim3(MB, 1), blk, 0, stream>>>(
      attn, Bhi + o_proj, Blo + o_proj, out, N_NODES, 128, 128, ProNone{},
      EpiResGate{b_proj, x, gmsa});

  // 7. P1 = silu(c) @ w_ada[:,384:640] + b  (sh_mlp|sc_mlp; gmsa dead)
  gemm_direct<ProSilu, EpiBias><<<dim3(MB, 2), blk, 0, stream>>>(
      c, Bhi + o_adam, Blo + o_adam, P1, N_NODES, 256, 128, ProSilu{}, EpiBias{b_ada + 384});

  // 8. xm = modulate(ln(x1), sh_mlp, sc_mlp)  (attn dead after step 6)
  ln_mod_kernel<<<dim3((N_NODES + 3) / 4), blk, 0, stream>>>(out, P1, xm);

  // 9. gmlp = silu(c) @ w_ada[:,640:768] + b  -> P3 tail (qkv dead after attn)
  gemm_direct<ProSilu, EpiBias><<<dim3(MB, 1), blk, 0, stream>>>(
      c, Bhi + o_gmlp, Blo + o_gmlp, gmlp, N_NODES, 128, 128, ProSilu{}, EpiBias{b_ada + 640});

  // 10. h1 = gelu(xm @ w_mlp1 + b_mlp1)  [N,512] over P1 + P3[:,0:256]
  gemm_direct<ProNone, EpiGelu><<<dim3(MB, 4), blk, 0, stream>>>(
      xm, Bhi + o_mlp1, Blo + o_mlp1, h1, N_NODES, 512, 128, ProNone{}, EpiGelu{b_mlp1});

  // 11. out = x1 + gmlp * (h1 @ w_mlp2 + b_mlp2)  (in-place: safe)
  gemm_direct<ProNone, EpiResGate><<<dim3(MB, 1), blk, 0, stream>>>(
      h1, Bhi + o_mlp2, Blo + o_mlp2, out, N_NODES, 128, 512, ProNone{},
      EpiResGate{b_mlp2, out, gmlp});
}

// Round 3
// 576.430 us; speedup vs baseline: 1.1064x; 1.0271x over previous
//
#include <hip/hip_runtime.h>
#include <math.h>

#define N_NODES 50000
#define HIDD 128
#define HEADS 8
#define HDIM 16
#define NE 800000

using short8 = __attribute__((ext_vector_type(8))) short;
using f32x4 = __attribute__((ext_vector_type(4))) float;

// ---------- dtype-robust edge-index load (clamped: can never fault) ----------
__device__ __forceinline__ int load_idx(const void* ei, int is64, long long pos) {
  long long v = is64 ? ((const long long*)ei)[pos]
                     : (long long)((const int*)ei)[pos];
  unsigned uv = (unsigned)v;
  return (uv < N_NODES) ? (int)uv : 0;
}

// int64 vs int32 detect: LE int64 < 2^31 has every odd int32 word == 0.
__global__ void detect_kernel(const unsigned* __restrict__ ei_raw, int* flag) {
  __shared__ int any_nonzero;
  if (threadIdx.x == 0) any_nonzero = 0;
  __syncthreads();
  if (threadIdx.x < 128) {
    if (ei_raw[2 * threadIdx.x + 1] != 0u) atomicOr(&any_nonzero, 1);
  }
  __syncthreads();
  if (threadIdx.x == 0) *flag = any_nonzero ? 0 : 1;  // 1 => int64
}

// ---------- ws-too-small probe: absmax ~= ws_size in MB ----------
__global__ __launch_bounds__(256) void probe_kernel(float* out, int n, float mb) {
  int i = blockIdx.x * 256 + threadIdx.x;
  if (i < n) out[i] = (i == 0) ? mb : 0.f;
}

// ---------- prologue / epilogue functors ----------
struct ProNone {
  __device__ __forceinline__ float operator()(float v, int, int) const { return v; }
};
struct ProSilu {
  __device__ __forceinline__ float operator()(float v, int, int) const {
    return v / (1.f + __expf(-v));
  }
};
struct EpiNone {
  __device__ __forceinline__ float operator()(float a, int, int) const { return a; }
};
struct EpiBias {
  const float* b;  // pre-offset on host
  __device__ __forceinline__ float operator()(float a, int, int c) const { return a + b[c]; }
};
struct EpiGelu {
  const float* b;
  __device__ __forceinline__ float operator()(float a, int, int c) const {
    float t = a + b[c];
    float u = 0.7978845608028654f * (t + 0.044715f * t * t * t);
    // tanh(u) = sign(u) * (1 - 2/(exp(2|u|)+1)); exp->inf gives exact +-1.
    float au = fabsf(u);
    float e = __expf(2.f * au);
    float th = __builtin_copysignf(1.f - 2.f / (e + 1.f), u);
    return 0.5f * t * (1.f + th);
  }
};
struct EpiResGate {  // xres[r,c] + gate[r,c] * (a + b[c]); gate/xres stride 128
  const float* b;
  const float* xres;
  const float* gate;
  __device__ __forceinline__ float operator()(float a, int r, int c) const {
    return xres[(size_t)r * HIDD + c] + gate[(size_t)r * HIDD + c] * (a + b[c]);
  }
};

// ---------- fused B pre-split: 8 segments, fragment-ordered bf16 hi/lo -------
// Element B[k][n] of segment s lands at:
//   lane = ((k>>3)&3)*16 + (n&15), j = k&7
//   dst  = dst_off + (((k>>5)*(N/16) + (n>>4))*64 + lane)*8 + j
struct CvTab {
  int end[8];
  int src_sel[8];
  int src_off[8];
  int ldb[8];
  int n[8];
  int dst_off[8];
};
__global__ __launch_bounds__(256) void convert_all_kernel(
    const float* __restrict__ p0, const float* __restrict__ p1,
    const float* __restrict__ p2, const float* __restrict__ p3,
    const float* __restrict__ p4, CvTab t, int total,
    unsigned short* __restrict__ hi, unsigned short* __restrict__ lo) {
  int idx = blockIdx.x * 256 + threadIdx.x;
  if (idx >= total) return;
  int s = 0;
#pragma unroll
  for (int j = 0; j < 7; j++) s += (idx >= t.end[j]) ? 1 : 0;
  int local = idx - (s ? t.end[s - 1] : 0);
  int N = t.n[s];
  int k = (unsigned)local / (unsigned)N;
  int n = local - k * N;
  const float* B;
  int sel = t.src_sel[s];
  B = (sel == 0) ? p0 : (sel == 1) ? p1 : (sel == 2) ? p2 : (sel == 3) ? p3 : p4;
  float f = B[(size_t)k * t.ldb[s] + t.src_off[s] + n];
  unsigned u = __float_as_uint(f);
  unsigned short hs = (unsigned short)(u >> 16);  // truncated bf16 hi
  float hf = __uint_as_float(u & 0xFFFF0000u);
  unsigned short ls = (unsigned short)(__float_as_uint(f - hf) >> 16);
  int lane = (((k >> 3) & 3) << 4) | (n & 15);
  int dst = t.dst_off[s] + (((k >> 5) * (N >> 4) + (n >> 4)) * 64 + lane) * 8 + (k & 7);
  hi[dst] = hs;
  lo[dst] = ls;
}

// ---------- MFMA split-bf16 GEMM v4 ------------------------------------------
// No LDS, no barriers. Each wave owns a 16-row x 128-col strip.
// AMODE 0: A f32 [M][K]; apply Pro; split to hi/lo in registers (3 MFMA/tile).
// AMODE 1: A bf16 ushort [M][K]; no conversion (2 MFMA/tile: a*(bhi+blo)).
// AMODE 2: A pre-split planes Av=hi, Av2=lo ushort [M][K]; 3 MFMA/tile, no VALU.
// OMODE 0: C f32 with epi.  OMODE 1: QKV row = q[128 f32]|k[128 bf16]|v[128 bf16].
// OMODE 2: C bf16(RNE) ushort [M][N] after epi.
template <class Pro, class Epi, int OMODE = 0, int AMODE = 0>
__global__ __launch_bounds__(256) void gemm_direct(
    const void* __restrict__ Av, const void* __restrict__ Av2,
    const unsigned short* __restrict__ Bhi, const unsigned short* __restrict__ Blo,
    void* __restrict__ Cv, int M, int N, int K, Pro pro, Epi epi) {
  const int tid = threadIdx.x;
  const int lane = tid & 63;
  const int wv = tid >> 6;
  const int quad = lane >> 4;
  const int ln15 = lane & 15;
  const int mrow0 = blockIdx.x * 64 + wv * 16;  // this wave's 16-row strip
  const int arow = mrow0 + ln15;                // row this lane loads for A
  const int col0 = blockIdx.y * 128;
  const int Nt = N >> 4;
  const int ntbase = col0 >> 4;
  const bool aok = (arow < M);
  const int KB = K >> 5;
  float* C = (float*)Cv;

  f32x4 acc[8] = {};

  for (int kb = 0; kb < KB; kb++) {
    short8 ahi = {}, alo = {};
    if constexpr (AMODE == 0) {
      const float* A = (const float*)Av;
      float4 a0 = make_float4(0.f, 0.f, 0.f, 0.f), a1 = a0;
      if (aok) {
        const float* ap = A + (size_t)arow * K + kb * 32 + quad * 8;
        a0 = *(const float4*)ap;
        a1 = *(const float4*)(ap + 4);
        int cb = kb * 32 + quad * 8;
        a0.x = pro(a0.x, arow, cb + 0); a0.y = pro(a0.y, arow, cb + 1);
        a0.z = pro(a0.z, arow, cb + 2); a0.w = pro(a0.w, arow, cb + 3);
        a1.x = pro(a1.x, arow, cb + 4); a1.y = pro(a1.y, arow, cb + 5);
        a1.z = pro(a1.z, arow, cb + 6); a1.w = pro(a1.w, arow, cb + 7);
      }
      float f[8] = {a0.x, a0.y, a0.z, a0.w, a1.x, a1.y, a1.z, a1.w};
      union { unsigned u[4]; short8 v; } ch, cl;
#pragma unroll
      for (int e = 0; e < 4; e++) {
        unsigned u0 = __float_as_uint(f[2 * e]);
        unsigned u1 = __float_as_uint(f[2 * e + 1]);
        ch.u[e] = (u0 >> 16) | (u1 & 0xFFFF0000u);
        float h0 = __uint_as_float(u0 & 0xFFFF0000u);
        float h1 = __uint_as_float(u1 & 0xFFFF0000u);
        cl.u[e] = (__float_as_uint(f[2 * e] - h0) >> 16) |
                  (__float_as_uint(f[2 * e + 1] - h1) & 0xFFFF0000u);
      }
      ahi = ch.v;
      alo = cl.v;
    } else if constexpr (AMODE == 1) {
      if (aok)
        ahi = *(const short8*)((const unsigned short*)Av + (size_t)arow * K + kb * 32 + quad * 8);
    } else {
      if (aok) {
        size_t aoff = (size_t)arow * K + kb * 32 + quad * 8;
        ahi = *(const short8*)((const unsigned short*)Av + aoff);
        alo = *(const short8*)((const unsigned short*)Av2 + aoff);
      }
    }

    const unsigned short* bph = Bhi + ((size_t)(kb * Nt + ntbase) * 64 + lane) * 8;
    const unsigned short* bpl = Blo + ((size_t)(kb * Nt + ntbase) * 64 + lane) * 8;
#pragma unroll
    for (int nt = 0; nt < 8; nt++) {
      short8 bhi = *(const short8*)(bph + nt * 512);
      short8 blo = *(const short8*)(bpl + nt * 512);
      if constexpr (AMODE != 1)
        acc[nt] = __builtin_amdgcn_mfma_f32_16x16x32_bf16(alo, bhi, acc[nt], 0, 0, 0);
      acc[nt] = __builtin_amdgcn_mfma_f32_16x16x32_bf16(ahi, blo, acc[nt], 0, 0, 0);
      acc[nt] = __builtin_amdgcn_mfma_f32_16x16x32_bf16(ahi, bhi, acc[nt], 0, 0, 0);
    }
  }

  // epilogue: D[row = quad*4+r][col = ln15] per 16x16 tile
#pragma unroll
  for (int nt = 0; nt < 8; nt++) {
    f32x4 a = acc[nt];
    int gc = col0 + nt * 16 + ln15;
#pragma unroll
    for (int r = 0; r < 4; r++) {
      int gr = mrow0 + quad * 4 + r;
      if (gr < M) {
        if constexpr (OMODE == 1) {
          if (gc < 128) {
            C[(size_t)gr * N + gc] = a[r];
          } else {
            unsigned u = __float_as_uint(a[r]);
            unsigned rr = (u + 0x7FFFu + ((u >> 16) & 1u)) >> 16;  // RNE bf16
            ((unsigned short*)(C + (size_t)gr * N))[128 + gc] = (unsigned short)rr;
          }
        } else if constexpr (OMODE == 2) {
          float v = epi(a[r], gr, gc);
          unsigned u = __float_as_uint(v);
          unsigned rr = (u + 0x7FFFu + ((u >> 16) & 1u)) >> 16;  // RNE bf16
          ((unsigned short*)Cv)[(size_t)gr * N + gc] = (unsigned short)rr;
        } else {
          C[(size_t)gr * N + gc] = epi(a[r], gr, gc);
        }
      }
    }
  }
}

// ---------- LN + modulate -> packed bf16 hi/lo planes -------------------------
// shsc rows = [sh(128)|sc(128)], stride 256. Output: xh/xl uint planes, each
// [row][64] uints (2 bf16 per uint, elem d in low half). hi = trunc, lo = exact
// residual — matches the GEMM's in-register split semantics bit-for-bit.
__global__ __launch_bounds__(256) void ln_mod_kernel(
    const float* __restrict__ x, const float* __restrict__ shsc,
    unsigned* __restrict__ xh, unsigned* __restrict__ xl) {
  int wave = threadIdx.x >> 6;
  int lane = threadIdx.x & 63;
  int row = blockIdx.x * 4 + wave;
  if (row >= N_NODES) return;
  float2 v = *(const float2*)(x + (size_t)row * HIDD + lane * 2);
  float s = v.x + v.y;
  float sq = v.x * v.x + v.y * v.y;
#pragma unroll
  for (int o = 32; o >= 1; o >>= 1) {
    s += __shfl_xor(s, o);
    sq += __shfl_xor(sq, o);
  }
  float m = s * (1.f / 128.f);
  float var = sq * (1.f / 128.f) - m * m;
  float rs = rsqrtf(var + 1e-6f);
  float2 sh = *(const float2*)(shsc + (size_t)row * 256 + lane * 2);
  float2 sc = *(const float2*)(shsc + (size_t)row * 256 + 128 + lane * 2);
  float ox = (v.x - m) * rs * (1.f + sc.x) + sh.x;
  float oy = (v.y - m) * rs * (1.f + sc.y) + sh.y;
  unsigned ux = __float_as_uint(ox), uy = __float_as_uint(oy);
  unsigned hx = ux & 0xFFFF0000u, hy = uy & 0xFFFF0000u;
  unsigned lx = __float_as_uint(ox - __uint_as_float(hx));
  unsigned ly = __float_as_uint(oy - __uint_as_float(hy));
  xh[(size_t)row * 64 + lane] = (ux >> 16) | hy;
  xl[(size_t)row * 64 + lane] = (lx >> 16) | (ly & 0xFFFF0000u);
}

// ---------- CSR build ----------
__global__ __launch_bounds__(256) void zero_int_kernel(int* p, int n) {
  int i = blockIdx.x * 256 + threadIdx.x;
  if (i < n) p[i] = 0;
}

__global__ __launch_bounds__(256) void hist_kernel(const void* __restrict__ ei,
                                                   const int* __restrict__ flag,
                                                   int* __restrict__ A) {
  int e = blockIdx.x * 256 + threadIdx.x;
  if (e >= NE) return;
  int dst = load_idx(ei, *flag, (long long)NE + e);
  atomicAdd(&A[dst + 1], 1);
}

// 3-phase scan
__global__ __launch_bounds__(1024) void scan1_kernel(int* __restrict__ A, int n,
                                                     int* __restrict__ bsum) {
  __shared__ int buf[2][1024];
  int i = blockIdx.x * 1024 + threadIdx.x;
  int val = (i < n) ? A[i] : 0;
  int pb = 0;
  buf[0][threadIdx.x] = val;
  __syncthreads();
#pragma unroll
  for (int off = 1; off < 1024; off <<= 1) {
    int t = buf[pb][threadIdx.x];
    if ((int)threadIdx.x >= off) t += buf[pb][threadIdx.x - off];
    buf[pb ^ 1][threadIdx.x] = t;
    pb ^= 1;
    __syncthreads();
  }
  int incl = buf[pb][threadIdx.x];
  if (i < n) A[i] = incl;
  if (threadIdx.x == 1023) bsum[blockIdx.x] = incl;
}
__global__ void scan2_kernel(int* __restrict__ bsum, int nb) {
  int l = threadIdx.x;  // 64 threads, nb <= 64
  int v = (l < nb) ? bsum[l] : 0;
#pragma unroll
  for (int off = 1; off < 64; off <<= 1) {
    int t = __shfl_up(v, off);
    if (l >= off) v += t;
  }
  if (l < nb) bsum[l] = v;
}
__global__ __launch_bounds__(256) void scan3_kernel(int* __restrict__ A, int n,
                                                    const int* __restrict__ bsum) {
  int i = blockIdx.x * 256 + threadIdx.x;
  int b = i >> 10;
  if (i < n && b > 0) A[i] += bsum[b - 1];
}

// scatter: pos = A[dst]++, col[pos] = src. Afterwards A[i] == orig rowptr[i+1].
__global__ __launch_bounds__(256) void scatter_kernel(const void* __restrict__ ei,
                                                      const int* __restrict__ flag,
                                                      int* __restrict__ A,
                                                      unsigned short* __restrict__ col) {
  int e = blockIdx.x * 256 + threadIdx.x;
  if (e >= NE) return;
  int is64 = *flag;
  int src = load_idx(ei, is64, e);
  int dst = load_idx(ei, is64, (long long)NE + e);
  int pos = atomicAdd(&A[dst], 1);
  col[pos] = (unsigned short)src;
}

// ---------- fused per-node attention, v3: bf16 k/v gather, 2 edges/iter ------
// qkv rows (1536B): q[128 f32] | k[128 bf16] | v[128 bf16] | 512B unused.
// Wave layout: lanes 0-31 even edges, lanes 32-63 odd edges; each lane owns 4
// contiguous dims (head = l32>>2); dot-reduce = 2 shfl_xor over 4-lane group.
// Max-free softmax: s = (q.k)/4, |s| << 88 for LN'd inputs; w = exp(min(s,60))
// is exact after normalization. Index prefetch decoupled 2 iters ahead so no
// serial col->gather chain. Gather: 256B/row (half of fp32) — the kernel was
// proven L2-fill-traffic-bound (r1: VALU cut, dur unchanged, FETCH identical).
__global__ __launch_bounds__(256) void node_attn_kernel(
    const int* __restrict__ A, const unsigned short* __restrict__ col,
    const float* __restrict__ qkv, float* __restrict__ attn) {
  int wave = threadIdx.x >> 6;
  int lane = threadIdx.x & 63;
  int half = lane >> 5;   // 0: even edges, 1: odd edges
  int l32 = lane & 31;    // dims l32*4 .. l32*4+3
  int node = blockIdx.x * 4 + wave;
  if (node >= N_NODES) return;
  int start = (node == 0) ? 0 : A[node - 1];
  int end = A[node];
  int deg = end - start;

  float4 q = *(const float4*)(qkv + (size_t)node * 384 + l32 * 4);
  float l = 0.f;
  float4 acc = make_float4(0.f, 0.f, 0.f, 0.f);

  if (deg > 0) {
    int itc = (deg + 1) >> 1;
    int last = end - 1;
    const unsigned* qu = (const unsigned*)qkv;
    // edge index for iteration it (clamped; clamped dups get w=0 via valid mask)
    auto eidx = [&](int it) {
      int e = start + 2 * it + half;
      return (e <= last) ? e : last;
    };
    int i_cur = col[eidx(0)];
    int i_nxt = col[eidx(1)];  // clamped-safe even when itc==1
    // k at uint idx 128+2*l32, v at 192+2*l32 within the 384-uint row
    uint2 kcw = *(const uint2*)(qu + (size_t)i_cur * 384 + 128 + 2 * l32);
    uint2 vcw = *(const uint2*)(qu + (size_t)i_cur * 384 + 192 + 2 * l32);
    for (int it = 0; it < itc; it++) {
      uint2 knw = kcw, vnw = vcw;
      if (it + 1 < itc) {
        knw = *(const uint2*)(qu + (size_t)i_nxt * 384 + 128 + 2 * l32);
        vnw = *(const uint2*)(qu + (size_t)i_nxt * 384 + 192 + 2 * l32);
      }
      i_nxt = col[eidx(it + 2)];  // prefetch index 2 iters ahead (clamped-safe)
      float kx = __uint_as_float(kcw.x << 16);
      float ky = __uint_as_float(kcw.x & 0xFFFF0000u);
      float kz = __uint_as_float(kcw.y << 16);
      float kw = __uint_as_float(kcw.y & 0xFFFF0000u);
      float s = q.x * kx + q.y * ky + q.z * kz + q.w * kw;
      s += __shfl_xor(s, 1);
      s += __shfl_xor(s, 2);
      s *= 0.25f;  // 1/sqrt(16)
      bool valid = (start + 2 * it + half) < end;
      float w = valid ? __expf(fminf(s, 60.f)) : 0.f;
      float vx = __uint_as_float(vcw.x << 16);
      float vy = __uint_as_float(vcw.x & 0xFFFF0000u);
      float vz = __uint_as_float(vcw.y << 16);
      float vw = __uint_as_float(vcw.y & 0xFFFF0000u);
      l += w;
      acc.x += w * vx;
      acc.y += w * vy;
      acc.z += w * vz;
      acc.w += w * vw;
      kcw = knw;
      vcw = vnw;
    }
  }
  // combine even/odd halves (both halves end with the full sums)
  l += __shfl_xor(l, 32);
  acc.x += __shfl_xor(acc.x, 32);
  acc.y += __shfl_xor(acc.y, 32);
  acc.z += __shfl_xor(acc.z, 32);
  acc.w += __shfl_xor(acc.w, 32);
  float inv = (l > 0.f) ? 1.f / l : 0.f;
  if (half == 0) {
    float4 o = make_float4(acc.x * inv, acc.y * inv, acc.z * inv, acc.w * inv);
    *(float4*)(attn + (size_t)node * HIDD + l32 * 4) = o;
  }
}

extern "C" void kernel_launch(void* const* d_in, const int* in_sizes, int n_in,
                              void* d_out, int out_size, void* d_ws, size_t ws_size,
                              hipStream_t stream) {
  const float* x      = (const float*)d_in[0];
  const void*  ei     = d_in[1];
  const float* c      = (const float*)d_in[2];
  const float* w_qkv  = (const float*)d_in[3];
  const float* w_proj = (const float*)d_in[4];
  const float* b_proj = (const float*)d_in[5];
  const float* w_mlp1 = (const float*)d_in[6];
  const float* b_mlp1 = (const float*)d_in[7];
  const float* w_mlp2 = (const float*)d_in[8];
  const float* b_mlp2 = (const float*)d_in[9];
  const float* w_ada  = (const float*)d_in[10];
  const float* b_ada  = (const float*)d_in[11];
  float* out = (float*)d_out;

  // ---- pool layout (floats): xm(128) | P1(256) | P3(384) + CSR + B planes ---
  const size_t NM = (size_t)N_NODES;
  float* pool = (float*)d_ws;
  float* xm    = pool;                       // N*128: xh|xl planes; attn overlay
  float* P1    = xm + NM * 128;              // N*256: ada shsc chunks; h1 bf16
  float* P3    = P1 + NM * 256;              // N*384: qkv; gmlp tail
  int*   Arow  = (int*)(P3 + NM * 384);      // 50048 ints
  unsigned short* col = (unsigned short*)(Arow + 50048);  // E ushort
  int*   eflag = (int*)(col + NE);           // 8 ints
  int*   bsum  = eflag + 8;                  // 64 ints
  unsigned short* Bhi = (unsigned short*)(bsum + 64);  // 294912
  unsigned short* Blo = Bhi + 294912;                  // 294912
  // overlays
  unsigned* xh = (unsigned*)xm;              // [N][64] uints (bf16 hi pairs)
  unsigned* xl = xh + NM * 64;               // [N][64] uints (bf16 lo pairs)
  float* attn  = xm;                         // after qkv GEMM, planes dead
  float* gmsa  = P1;                         // [N,128] after ln1
  unsigned short* h1 = (unsigned short*)P1;  // [N,512] bf16 (fits P1 exactly)
  float* gmlp  = P3 + NM * 256;              // [N,128] tail of P3

  // B-plane element offsets
  const int o_qkv = 0, o_ada0 = 49152, o_gmsa = 81920, o_adam = 98304,
            o_gmlp = 131072, o_proj = 147456, o_mlp1 = 163840, o_mlp2 = 229376;
  const int cv_total = 294912;

  const size_t req_bytes = (NM * 768) * 4 + 50048 * 4 + NE * 2 + 32 + 256 +
                           (size_t)cv_total * 2 * 2;
  dim3 blk(256);
  if (ws_size < req_bytes) {
    probe_kernel<<<dim3((out_size + 255) / 256), blk, 0, stream>>>(
        out, out_size, (float)(ws_size >> 20));
    return;
  }

  const int MB = (N_NODES + 63) / 64;   // 782 row-blocks (64 rows, 4 waves)
  const int EB = (NE + 255) / 256;
  const int SB = (N_NODES + 1 + 1023) / 1024;  // 49 scan blocks

  // 0. dtype detect + CSR build
  detect_kernel<<<dim3(1), blk, 0, stream>>>((const unsigned*)ei, eflag);
  zero_int_kernel<<<dim3((N_NODES + 1 + 255) / 256), blk, 0, stream>>>(Arow, N_NODES + 1);
  hist_kernel<<<dim3(EB), blk, 0, stream>>>(ei, eflag, Arow);
  scan1_kernel<<<dim3(SB), dim3(1024), 0, stream>>>(Arow, N_NODES + 1, bsum);
  scan2_kernel<<<dim3(1), dim3(64), 0, stream>>>(bsum, SB);
  scan3_kernel<<<dim3((N_NODES + 1 + 255) / 256), blk, 0, stream>>>(Arow, N_NODES + 1, bsum);
  scatter_kernel<<<dim3(EB), blk, 0, stream>>>(ei, eflag, Arow, col);

  // 0b. pre-split all weights into fragment-ordered bf16 hi/lo planes (1 launch)
  {
    CvTab t;
    // seg:            qkv     ada0    gmsa    adam    gmlp    proj    mlp1    mlp2
    int sel[8]     = { 0,      1,      1,      1,      1,      2,      3,      4 };
    int soff[8]    = { 0,      0,      256,    384,    640,    0,      0,      0 };
    int ldb[8]     = { 384,    768,    768,    768,    768,    128,    512,    128 };
    int nn[8]      = { 384,    256,    128,    256,    128,    128,    512,    128 };
    int doff[8]    = { o_qkv,  o_ada0, o_gmsa, o_adam, o_gmlp, o_proj, o_mlp1, o_mlp2 };
    int cnt[8]     = { 49152,  32768,  16384,  32768,  16384,  16384,  65536,  65536 };
    int accum = 0;
    for (int s = 0; s < 8; s++) {
      accum += cnt[s];
      t.end[s] = accum; t.src_sel[s] = sel[s]; t.src_off[s] = soff[s];
      t.ldb[s] = ldb[s]; t.n[s] = nn[s]; t.dst_off[s] = doff[s];
    }
    convert_all_kernel<<<dim3((cv_total + 255) / 256), blk, 0, stream>>>(
        w_qkv, w_ada, w_proj, w_mlp1, w_mlp2, t, cv_total, Bhi, Blo);
  }

  // 1. P1 = silu(c) @ w_ada[:,0:256] + b  (sh_msa|sc_msa)
  gemm_direct<ProSilu, EpiBias, 0, 0><<<dim3(MB, 2), blk, 0, stream>>>(
      c, nullptr, Bhi + o_ada0, Blo + o_ada0, P1, N_NODES, 256, 128,
      ProSilu{}, EpiBias{b_ada});

  // 2. xm planes = modulate(ln(x), sh_msa, sc_msa)  -> xh|xl
  ln_mod_kernel<<<dim3((N_NODES + 3) / 4), blk, 0, stream>>>(x, P1, xh, xl);

  // 3. P3 = xm @ w_qkv  [N,384] = q(f32)|k(bf16)|v(bf16)   (A from planes)
  gemm_direct<ProNone, EpiNone, 1, 2><<<dim3(MB, 3), blk, 0, stream>>>(
      xh, xl, Bhi + o_qkv, Blo + o_qkv, P3, N_NODES, 384, 128,
      ProNone{}, EpiNone{});

  // 4. fused graph attention -> attn (overlays xm planes; dead after step 3)
  node_attn_kernel<<<dim3((N_NODES + 3) / 4), blk, 0, stream>>>(Arow, col, P3, attn);

  // 5. gmsa = silu(c) @ w_ada[:,256:384] + b  (P1 shsc dead after ln1)
  gemm_direct<ProSilu, EpiBias, 0, 0><<<dim3(MB, 1), blk, 0, stream>>>(
      c, nullptr, Bhi + o_gmsa, Blo + o_gmsa, gmsa, N_NODES, 128, 128,
      ProSilu{}, EpiBias{b_ada + 256});

  // 6. x1(d_out) = x + gmsa * (attn @ w_proj + b_proj)
  gemm_direct<ProNone, EpiResGate, 0, 0><<<dim3(MB, 1), blk, 0, stream>>>(
      attn, nullptr, Bhi + o_proj, Blo + o_proj, out, N_NODES, 128, 128,
      ProNone{}, EpiResGate{b_proj, x, gmsa});

  // 7. P1 = silu(c) @ w_ada[:,384:640] + b  (sh_mlp|sc_mlp; gmsa dead)
  gemm_direct<ProSilu, EpiBias, 0, 0><<<dim3(MB, 2), blk, 0, stream>>>(
      c, nullptr, Bhi + o_adam, Blo + o_adam, P1, N_NODES, 256, 128,
      ProSilu{}, EpiBias{b_ada + 384});

  // 8. xm planes = modulate(ln(x1), sh_mlp, sc_mlp)  (attn dead after step 6)
  ln_mod_kernel<<<dim3((N_NODES + 3) / 4), blk, 0, stream>>>(out, P1, xh, xl);

  // 9. gmlp = silu(c) @ w_ada[:,640:768] + b  -> P3 tail (qkv dead after attn)
  gemm_direct<ProSilu, EpiBias, 0, 0><<<dim3(MB, 1), blk, 0, stream>>>(
      c, nullptr, Bhi + o_gmlp, Blo + o_gmlp, gmlp, N_NODES, 128, 128,
      ProSilu{}, EpiBias{b_ada + 640});

  // 10. h1 = gelu(xm @ w_mlp1 + b_mlp1) -> bf16 [N,512] in P1 (shsc dead)
  gemm_direct<ProNone, EpiGelu, 2, 2><<<dim3(MB, 4), blk, 0, stream>>>(
      xh, xl, Bhi + o_mlp1, Blo + o_mlp1, h1, N_NODES, 512, 128,
      ProNone{}, EpiGelu{b_mlp1});

  // 11. out = x1 + gmlp * (h1 @ w_mlp2 + b_mlp2)  (A bf16; in-place: safe)
  gemm_direct<ProNone, EpiResGate, 0, 1><<<dim3(MB, 1), blk, 0, stream>>>(
      h1, nullptr, Bhi + o_mlp2, Blo + o_mlp2, out, N_NODES, 128, 512,
      ProNone{}, EpiResGate{b_mlp2, out, gmlp});
}

// Round 4
// 550.797 us; speedup vs baseline: 1.1578x; 1.0465x over previous
//
#include <hip/hip_runtime.h>
#include <math.h>

#define N_NODES 50000
#define HIDD 128
#define HEADS 8
#define HDIM 16
#define NE 800000

using short8 = __attribute__((ext_vector_type(8))) short;
using f32x4 = __attribute__((ext_vector_type(4))) float;

// ---------- dtype-robust edge-index load (clamped: can never fault) ----------
__device__ __forceinline__ int load_idx(const void* ei, int is64, long long pos) {
  long long v = is64 ? ((const long long*)ei)[pos]
                     : (long long)((const int*)ei)[pos];
  unsigned uv = (unsigned)v;
  return (uv < N_NODES) ? (int)uv : 0;
}

// int64 vs int32 detect: LE int64 < 2^31 has every odd int32 word == 0.
__global__ void detect_kernel(const unsigned* __restrict__ ei_raw, int* flag) {
  __shared__ int any_nonzero;
  if (threadIdx.x == 0) any_nonzero = 0;
  __syncthreads();
  if (threadIdx.x < 128) {
    if (ei_raw[2 * threadIdx.x + 1] != 0u) atomicOr(&any_nonzero, 1);
  }
  __syncthreads();
  if (threadIdx.x == 0) *flag = any_nonzero ? 0 : 1;  // 1 => int64
}

// ---------- ws-too-small probe: absmax ~= ws_size in MB ----------
__global__ __launch_bounds__(256) void probe_kernel(float* out, int n, float mb) {
  int i = blockIdx.x * 256 + threadIdx.x;
  if (i < n) out[i] = (i == 0) ? mb : 0.f;
}

// ---------- prologue / epilogue functors ----------
struct ProNone {
  __device__ __forceinline__ float operator()(float v, int, int) const { return v; }
};
struct ProSilu {
  __device__ __forceinline__ float operator()(float v, int, int) const {
    return v / (1.f + __expf(-v));
  }
};
struct EpiNone {
  __device__ __forceinline__ float operator()(float a, int, int) const { return a; }
};
struct EpiBias {
  const float* b;
  __device__ __forceinline__ float operator()(float a, int, int c) const { return a + b[c]; }
};
struct EpiGelu {
  const float* b;
  __device__ __forceinline__ float operator()(float a, int, int c) const {
    float t = a + b[c];
    float u = 0.7978845608028654f * (t + 0.044715f * t * t * t);
    // tanh(u) = sign(u) * (1 - 2/(exp(2|u|)+1)); exp->inf gives exact +-1.
    float au = fabsf(u);
    float e = __expf(2.f * au);
    float th = __builtin_copysignf(1.f - 2.f / (e + 1.f), u);
    return 0.5f * t * (1.f + th);
  }
};
struct EpiResGateB {  // xres[r,c] + gate_bf16[r,c] * (a + b[c]); gate row stride 768
  const float* b;
  const float* xres;
  const unsigned short* gate;  // bf16 plane, pre-offset to the gate column block
  __device__ __forceinline__ float operator()(float a, int r, int c) const {
    float g = __uint_as_float((unsigned)gate[(size_t)r * 768 + c] << 16);
    return xres[(size_t)r * HIDD + c] + g * (a + b[c]);
  }
};

// ---------- fused B pre-split: fragment-ordered bf16 hi/lo planes ------------
// Element B[k][n] of segment s lands at:
//   lane = ((k>>3)&3)*16 + (n&15), j = k&7
//   dst  = dst_off + (((k>>5)*(N/16) + (n>>4))*64 + lane)*8 + j
struct CvTab {
  int end[8];
  int src_sel[8];
  int src_off[8];
  int ldb[8];
  int n[8];
  int dst_off[8];
};
__global__ __launch_bounds__(256) void convert_all_kernel(
    const float* __restrict__ p0, const float* __restrict__ p1,
    const float* __restrict__ p2, const float* __restrict__ p3,
    const float* __restrict__ p4, CvTab t, int total,
    unsigned short* __restrict__ hi, unsigned short* __restrict__ lo) {
  int idx = blockIdx.x * 256 + threadIdx.x;
  if (idx >= total) return;
  int s = 0;
#pragma unroll
  for (int j = 0; j < 7; j++) s += (idx >= t.end[j]) ? 1 : 0;
  int local = idx - (s ? t.end[s - 1] : 0);
  int N = t.n[s];
  int k = (unsigned)local / (unsigned)N;
  int n = local - k * N;
  const float* B;
  int sel = t.src_sel[s];
  B = (sel == 0) ? p0 : (sel == 1) ? p1 : (sel == 2) ? p2 : (sel == 3) ? p3 : p4;
  float f = B[(size_t)k * t.ldb[s] + t.src_off[s] + n];
  unsigned u = __float_as_uint(f);
  unsigned short hs = (unsigned short)(u >> 16);  // truncated bf16 hi
  float hf = __uint_as_float(u & 0xFFFF0000u);
  unsigned short ls = (unsigned short)(__float_as_uint(f - hf) >> 16);
  int lane = (((k >> 3) & 3) << 4) | (n & 15);
  int dst = t.dst_off[s] + (((k >> 5) * (N >> 4) + (n >> 4)) * 64 + lane) * 8 + (k & 7);
  hi[dst] = hs;
  lo[dst] = ls;
}

// ---------- MFMA split-bf16 GEMM v5 ------------------------------------------
// No LDS, no barriers. Each wave owns a 16-row x 128-col strip.
// AMODE 0: A f32 [M][K]; apply Pro; split hi/lo in registers (3 MFMA/tile).
// AMODE 1: A bf16 ushort [M][K]; 2 MFMA/tile (a*(bhi+blo)).
// AMODE 2: A pre-split planes Av=hi, Av2=lo ushort [M][K]; 3 MFMA/tile, no VALU.
// OMODE 0: C f32 [M][N] with epi.
// OMODE 1: QKV row (256 f32 stride): q[128 f32] | kv interleaved bf16
//          (group g: k[4g..4g+3] then v[4g..4g+3], 8 ushorts per group).
// OMODE 2: C bf16(RNE) ushort [M][N] after epi.
template <class Pro, class Epi, int OMODE = 0, int AMODE = 0>
__global__ __launch_bounds__(256) void gemm_direct(
    const void* __restrict__ Av, const void* __restrict__ Av2,
    const unsigned short* __restrict__ Bhi, const unsigned short* __restrict__ Blo,
    void* __restrict__ Cv, int M, int N, int K, Pro pro, Epi epi) {
  const int tid = threadIdx.x;
  const int lane = tid & 63;
  const int wv = tid >> 6;
  const int quad = lane >> 4;
  const int ln15 = lane & 15;
  const int mrow0 = blockIdx.x * 64 + wv * 16;  // this wave's 16-row strip
  const int arow = mrow0 + ln15;                // row this lane loads for A
  const int col0 = blockIdx.y * 128;
  const int Nt = N >> 4;
  const int ntbase = col0 >> 4;
  const bool aok = (arow < M);
  const int KB = K >> 5;
  float* C = (float*)Cv;

  f32x4 acc[8] = {};

  for (int kb = 0; kb < KB; kb++) {
    short8 ahi = {}, alo = {};
    if constexpr (AMODE == 0) {
      const float* A = (const float*)Av;
      float4 a0 = make_float4(0.f, 0.f, 0.f, 0.f), a1 = a0;
      if (aok) {
        const float* ap = A + (size_t)arow * K + kb * 32 + quad * 8;
        a0 = *(const float4*)ap;
        a1 = *(const float4*)(ap + 4);
        int cb = kb * 32 + quad * 8;
        a0.x = pro(a0.x, arow, cb + 0); a0.y = pro(a0.y, arow, cb + 1);
        a0.z = pro(a0.z, arow, cb + 2); a0.w = pro(a0.w, arow, cb + 3);
        a1.x = pro(a1.x, arow, cb + 4); a1.y = pro(a1.y, arow, cb + 5);
        a1.z = pro(a1.z, arow, cb + 6); a1.w = pro(a1.w, arow, cb + 7);
      }
      float f[8] = {a0.x, a0.y, a0.z, a0.w, a1.x, a1.y, a1.z, a1.w};
      union { unsigned u[4]; short8 v; } ch, cl;
#pragma unroll
      for (int e = 0; e < 4; e++) {
        unsigned u0 = __float_as_uint(f[2 * e]);
        unsigned u1 = __float_as_uint(f[2 * e + 1]);
        ch.u[e] = (u0 >> 16) | (u1 & 0xFFFF0000u);
        float h0 = __uint_as_float(u0 & 0xFFFF0000u);
        float h1 = __uint_as_float(u1 & 0xFFFF0000u);
        cl.u[e] = (__float_as_uint(f[2 * e] - h0) >> 16) |
                  (__float_as_uint(f[2 * e + 1] - h1) & 0xFFFF0000u);
      }
      ahi = ch.v;
      alo = cl.v;
    } else if constexpr (AMODE == 1) {
      if (aok)
        ahi = *(const short8*)((const unsigned short*)Av + (size_t)arow * K + kb * 32 + quad * 8);
    } else {
      if (aok) {
        size_t aoff = (size_t)arow * K + kb * 32 + quad * 8;
        ahi = *(const short8*)((const unsigned short*)Av + aoff);
        alo = *(const short8*)((const unsigned short*)Av2 + aoff);
      }
    }

    const unsigned short* bph = Bhi + ((size_t)(kb * Nt + ntbase) * 64 + lane) * 8;
    const unsigned short* bpl = Blo + ((size_t)(kb * Nt + ntbase) * 64 + lane) * 8;
#pragma unroll
    for (int nt = 0; nt < 8; nt++) {
      short8 bhi = *(const short8*)(bph + nt * 512);
      short8 blo = *(const short8*)(bpl + nt * 512);
      if constexpr (AMODE != 1)
        acc[nt] = __builtin_amdgcn_mfma_f32_16x16x32_bf16(alo, bhi, acc[nt], 0, 0, 0);
      acc[nt] = __builtin_amdgcn_mfma_f32_16x16x32_bf16(ahi, blo, acc[nt], 0, 0, 0);
      acc[nt] = __builtin_amdgcn_mfma_f32_16x16x32_bf16(ahi, bhi, acc[nt], 0, 0, 0);
    }
  }

  // epilogue: D[row = quad*4+r][col = ln15] per 16x16 tile
#pragma unroll
  for (int nt = 0; nt < 8; nt++) {
    f32x4 a = acc[nt];
    int gc = col0 + nt * 16 + ln15;
#pragma unroll
    for (int r = 0; r < 4; r++) {
      int gr = mrow0 + quad * 4 + r;
      if (gr < M) {
        if constexpr (OMODE == 1) {
          float* crow = C + (size_t)gr * 256;  // physical row: 256 f32 (1024 B)
          if (gc < 128) {
            crow[gc] = a[r];
          } else {
            unsigned u = __float_as_uint(a[r]);
            unsigned rr = (u + 0x7FFFu + ((u >> 16) & 1u)) >> 16;  // RNE bf16
            unsigned short* kv = (unsigned short*)crow + 256;
            int c = gc - 128;
            int idx = (c < 128) ? (((c >> 2) << 3) + (c & 3))            // k slot
                                : ((((c - 128) >> 2) << 3) + 4 + ((c - 128) & 3));  // v slot
            kv[idx] = (unsigned short)rr;
          }
        } else if constexpr (OMODE == 2) {
          float v = epi(a[r], gr, gc);
          unsigned u = __float_as_uint(v);
          unsigned rr = (u + 0x7FFFu + ((u >> 16) & 1u)) >> 16;  // RNE bf16
          ((unsigned short*)Cv)[(size_t)gr * N + gc] = (unsigned short)rr;
        } else {
          C[(size_t)gr * N + gc] = epi(a[r], gr, gc);
        }
      }
    }
  }
}

// ---------- LN + modulate -> packed bf16 hi/lo planes -------------------------
// sh/sc come from the bf16 ada plane (row stride 768 ushorts = 384 uints);
// `sa` is pre-offset to the sh column block; sc is +128 cols (+64 uints).
// Output planes xh/xl: [row][64] uints (2 bf16 per uint; hi=trunc, lo=residual)
// — bit-identical to the GEMM's in-register split semantics.
__global__ __launch_bounds__(256) void ln_mod_kernel(
    const float* __restrict__ x, const unsigned* __restrict__ sa,
    unsigned* __restrict__ xh, unsigned* __restrict__ xl) {
  int wave = threadIdx.x >> 6;
  int lane = threadIdx.x & 63;
  int row = blockIdx.x * 4 + wave;
  if (row >= N_NODES) return;
  float2 v = *(const float2*)(x + (size_t)row * HIDD + lane * 2);
  float s = v.x + v.y;
  float sq = v.x * v.x + v.y * v.y;
#pragma unroll
  for (int o = 32; o >= 1; o >>= 1) {
    s += __shfl_xor(s, o);
    sq += __shfl_xor(sq, o);
  }
  float m = s * (1.f / 128.f);
  float var = sq * (1.f / 128.f) - m * m;
  float rs = rsqrtf(var + 1e-6f);
  unsigned shw = sa[(size_t)row * 384 + lane];
  unsigned scw = sa[(size_t)row * 384 + 64 + lane];
  float shx = __uint_as_float(shw << 16), shy = __uint_as_float(shw & 0xFFFF0000u);
  float scx = __uint_as_float(scw << 16), scy = __uint_as_float(scw & 0xFFFF0000u);
  float ox = (v.x - m) * rs * (1.f + scx) + shx;
  float oy = (v.y - m) * rs * (1.f + scy) + shy;
  unsigned ux = __float_as_uint(ox), uy = __float_as_uint(oy);
  unsigned hx = ux & 0xFFFF0000u, hy = uy & 0xFFFF0000u;
  unsigned lx = __float_as_uint(ox - __uint_as_float(hx));
  unsigned ly = __float_as_uint(oy - __uint_as_float(hy));
  xh[(size_t)row * 64 + lane] = (ux >> 16) | hy;
  xl[(size_t)row * 64 + lane] = (lx >> 16) | (ly & 0xFFFF0000u);
}

// ---------- CSR build ----------
__global__ __launch_bounds__(256) void zero_int_kernel(int* p, int n) {
  int i = blockIdx.x * 256 + threadIdx.x;
  if (i < n) p[i] = 0;
}

__global__ __launch_bounds__(256) void hist_kernel(const void* __restrict__ ei,
                                                   const int* __restrict__ flag,
                                                   int* __restrict__ A) {
  int e = blockIdx.x * 256 + threadIdx.x;
  if (e >= NE) return;
  int dst = load_idx(ei, *flag, (long long)NE + e);
  atomicAdd(&A[dst + 1], 1);
}

// 3-phase scan
__global__ __launch_bounds__(1024) void scan1_kernel(int* __restrict__ A, int n,
                                                     int* __restrict__ bsum) {
  __shared__ int buf[2][1024];
  int i = blockIdx.x * 1024 + threadIdx.x;
  int val = (i < n) ? A[i] : 0;
  int pb = 0;
  buf[0][threadIdx.x] = val;
  __syncthreads();
#pragma unroll
  for (int off = 1; off < 1024; off <<= 1) {
    int t = buf[pb][threadIdx.x];
    if ((int)threadIdx.x >= off) t += buf[pb][threadIdx.x - off];
    buf[pb ^ 1][threadIdx.x] = t;
    pb ^= 1;
    __syncthreads();
  }
  int incl = buf[pb][threadIdx.x];
  if (i < n) A[i] = incl;
  if (threadIdx.x == 1023) bsum[blockIdx.x] = incl;
}
__global__ void scan2_kernel(int* __restrict__ bsum, int nb) {
  int l = threadIdx.x;  // 64 threads, nb <= 64
  int v = (l < nb) ? bsum[l] : 0;
#pragma unroll
  for (int off = 1; off < 64; off <<= 1) {
    int t = __shfl_up(v, off);
    if (l >= off) v += t;
  }
  if (l < nb) bsum[l] = v;
}
__global__ __launch_bounds__(256) void scan3_kernel(int* __restrict__ A, int n,
                                                    const int* __restrict__ bsum) {
  int i = blockIdx.x * 256 + threadIdx.x;
  int b = i >> 10;
  if (i < n && b > 0) A[i] += bsum[b - 1];
}

// scatter: pos = A[dst]++, col[pos] = src. Afterwards A[i] == orig rowptr[i+1].
__global__ __launch_bounds__(256) void scatter_kernel(const void* __restrict__ ei,
                                                      const int* __restrict__ flag,
                                                      int* __restrict__ A,
                                                      unsigned short* __restrict__ col) {
  int e = blockIdx.x * 256 + threadIdx.x;
  if (e >= NE) return;
  int is64 = *flag;
  int src = load_idx(ei, is64, e);
  int dst = load_idx(ei, is64, (long long)NE + e);
  int pos = atomicAdd(&A[dst], 1);
  col[pos] = (unsigned short)src;
}

// ---------- fused per-node attention, v4: interleaved kv, 1 load/edge --------
// qkv rows (1024B, 256 f32 stride): q[128 f32] | kv interleaved bf16 (group g:
// k[4g..4g+3] | v[4g..4g+3], 16 B per group). Lane l32 owns group l32 → ONE
// uint4 load per edge covers its k and v. Lanes 0-31 even edges, 32-63 odd.
// Max-free softmax (s bounded << 88 for LN'd inputs); 2-deep index prefetch.
__global__ __launch_bounds__(256) void node_attn_kernel(
    const int* __restrict__ A, const unsigned short* __restrict__ col,
    const float* __restrict__ qkv, float* __restrict__ attn) {
  int wave = threadIdx.x >> 6;
  int lane = threadIdx.x & 63;
  int half = lane >> 5;   // 0: even edges, 1: odd edges
  int l32 = lane & 31;    // dims l32*4 .. l32*4+3
  int node = blockIdx.x * 4 + wave;
  if (node >= N_NODES) return;
  int start = (node == 0) ? 0 : A[node - 1];
  int end = A[node];
  int deg = end - start;

  float4 q = *(const float4*)(qkv + (size_t)node * 256 + l32 * 4);
  float l = 0.f;
  float4 acc = make_float4(0.f, 0.f, 0.f, 0.f);

  if (deg > 0) {
    int itc = (deg + 1) >> 1;
    int last = end - 1;
    const unsigned* qu = (const unsigned*)qkv;
    auto eidx = [&](int it) {
      int e = start + 2 * it + half;
      return (e <= last) ? e : last;
    };
    int i_cur = col[eidx(0)];
    int i_nxt = col[eidx(1)];
    uint4 kvc = *(const uint4*)(qu + (size_t)i_cur * 256 + 128 + 4 * l32);
    for (int it = 0; it < itc; it++) {
      uint4 kvn = kvc;
      if (it + 1 < itc)
        kvn = *(const uint4*)(qu + (size_t)i_nxt * 256 + 128 + 4 * l32);
      i_nxt = col[eidx(it + 2)];  // prefetch index 2 iters ahead (clamped-safe)
      float kx = __uint_as_float(kvc.x << 16);
      float ky = __uint_as_float(kvc.x & 0xFFFF0000u);
      float kz = __uint_as_float(kvc.y << 16);
      float kw = __uint_as_float(kvc.y & 0xFFFF0000u);
      float s = q.x * kx + q.y * ky + q.z * kz + q.w * kw;
      s += __shfl_xor(s, 1);
      s += __shfl_xor(s, 2);
      s *= 0.25f;  // 1/sqrt(16)
      bool valid = (start + 2 * it + half) < end;
      float w = valid ? __expf(fminf(s, 60.f)) : 0.f;
      float vx = __uint_as_float(kvc.z << 16);
      float vy = __uint_as_float(kvc.z & 0xFFFF0000u);
      float vz = __uint_as_float(kvc.w << 16);
      float vw = __uint_as_float(kvc.w & 0xFFFF0000u);
      l += w;
      acc.x += w * vx;
      acc.y += w * vy;
      acc.z += w * vz;
      acc.w += w * vw;
      kvc = kvn;
    }
  }
  // combine even/odd halves (both halves end with the full sums)
  l += __shfl_xor(l, 32);
  acc.x += __shfl_xor(acc.x, 32);
  acc.y += __shfl_xor(acc.y, 32);
  acc.z += __shfl_xor(acc.z, 32);
  acc.w += __shfl_xor(acc.w, 32);
  float inv = (l > 0.f) ? 1.f / l : 0.f;
  if (half == 0) {
    float4 o = make_float4(acc.x * inv, acc.y * inv, acc.z * inv, acc.w * inv);
    *(float4*)(attn + (size_t)node * HIDD + l32 * 4) = o;
  }
}

extern "C" void kernel_launch(void* const* d_in, const int* in_sizes, int n_in,
                              void* d_out, int out_size, void* d_ws, size_t ws_size,
                              hipStream_t stream) {
  const float* x      = (const float*)d_in[0];
  const void*  ei     = d_in[1];
  const float* c      = (const float*)d_in[2];
  const float* w_qkv  = (const float*)d_in[3];
  const float* w_proj = (const float*)d_in[4];
  const float* b_proj = (const float*)d_in[5];
  const float* w_mlp1 = (const float*)d_in[6];
  const float* b_mlp1 = (const float*)d_in[7];
  const float* w_mlp2 = (const float*)d_in[8];
  const float* b_mlp2 = (const float*)d_in[9];
  const float* w_ada  = (const float*)d_in[10];
  const float* b_ada  = (const float*)d_in[11];
  float* out = (float*)d_out;

  // ---- pool layout (bytes/node): ada bf16[768] (1536) | buf1 (512) | buf2
  // (1024) = 3072 B/node (same as before) + CSR + B planes -------------------
  const size_t NM = (size_t)N_NODES;
  unsigned short* ada = (unsigned short*)d_ws;   // [N][768] bf16: sh|sc|g msa, sh|sc|g mlp
  float* buf1 = (float*)(ada + NM * 768);        // [N][128] f32: xh|xl planes OR attn out
  float* buf2 = buf1 + NM * 128;                 // [N][256] f32: qkv rows OR h1 bf16
  int*   Arow  = (int*)(buf2 + NM * 256);        // 50048 ints
  unsigned short* col = (unsigned short*)(Arow + 50048);  // E ushort
  int*   eflag = (int*)(col + NE);               // 8 ints
  int*   bsum  = eflag + 8;                      // 64 ints
  unsigned short* Bhi = (unsigned short*)(bsum + 64);  // 294912
  unsigned short* Blo = Bhi + 294912;                  // 294912
  // overlays
  unsigned* xh = (unsigned*)buf1;                // [N][64] uints (bf16 hi pairs)
  unsigned* xl = xh + NM * 64;                   // [N][64] uints (bf16 lo pairs)
  float* attnb = buf1;                           // [N][128] f32 (after qkv GEMM)
  float* qkv   = buf2;                           // [N][256] f32-stride qkv rows
  unsigned short* h1 = (unsigned short*)buf2;    // [N][512] bf16 (after attn)

  // B-plane element offsets
  const int o_qkv = 0, o_ada = 49152, o_proj = 147456, o_mlp1 = 163840,
            o_mlp2 = 229376;
  const int cv_total = 294912;

  const size_t req_bytes = (NM * 768) * 4 + 50048 * 4 + NE * 2 + 32 + 256 +
                           (size_t)cv_total * 2 * 2;
  dim3 blk(256);
  if (ws_size < req_bytes) {
    probe_kernel<<<dim3((out_size + 255) / 256), blk, 0, stream>>>(
        out, out_size, (float)(ws_size >> 20));
    return;
  }

  const int MB = (N_NODES + 63) / 64;   // 782 row-blocks (64 rows, 4 waves)
  const int EB = (NE + 255) / 256;
  const int SB = (N_NODES + 1 + 1023) / 1024;  // 49 scan blocks

  // 0. dtype detect + CSR build
  detect_kernel<<<dim3(1), blk, 0, stream>>>((const unsigned*)ei, eflag);
  zero_int_kernel<<<dim3((N_NODES + 1 + 255) / 256), blk, 0, stream>>>(Arow, N_NODES + 1);
  hist_kernel<<<dim3(EB), blk, 0, stream>>>(ei, eflag, Arow);
  scan1_kernel<<<dim3(SB), dim3(1024), 0, stream>>>(Arow, N_NODES + 1, bsum);
  scan2_kernel<<<dim3(1), dim3(64), 0, stream>>>(bsum, SB);
  scan3_kernel<<<dim3((N_NODES + 1 + 255) / 256), blk, 0, stream>>>(Arow, N_NODES + 1, bsum);
  scatter_kernel<<<dim3(EB), blk, 0, stream>>>(ei, eflag, Arow, col);

  // 0b. pre-split all weights into fragment-ordered bf16 hi/lo planes (1 launch)
  {
    CvTab t;
    // seg:            qkv     ada     proj    mlp1    mlp2    (3 dummies)
    int sel[8]     = { 0,      1,      2,      3,      4,      0, 0, 0 };
    int soff[8]    = { 0,      0,      0,      0,      0,      0, 0, 0 };
    int ldb[8]     = { 384,    768,    128,    512,    128,    1, 1, 1 };
    int nn[8]      = { 384,    768,    128,    512,    128,    1, 1, 1 };
    int doff[8]    = { o_qkv,  o_ada,  o_proj, o_mlp1, o_mlp2, 0, 0, 0 };
    int cnt[8]     = { 49152,  98304,  16384,  65536,  65536,  0, 0, 0 };
    int accum = 0;
    for (int s = 0; s < 8; s++) {
      accum += cnt[s];
      t.end[s] = accum; t.src_sel[s] = sel[s]; t.src_off[s] = soff[s];
      t.ldb[s] = ldb[s]; t.n[s] = nn[s]; t.dst_off[s] = doff[s];
    }
    convert_all_kernel<<<dim3((cv_total + 255) / 256), blk, 0, stream>>>(
        w_qkv, w_ada, w_proj, w_mlp1, w_mlp2, t, cv_total, Bhi, Blo);
  }

  // 1. ada = silu(c) @ w_ada + b_ada  -> bf16 [N,768] (all 6 mod vectors, once)
  gemm_direct<ProSilu, EpiBias, 2, 0><<<dim3(MB, 6), blk, 0, stream>>>(
      c, nullptr, Bhi + o_ada, Blo + o_ada, ada, N_NODES, 768, 128,
      ProSilu{}, EpiBias{b_ada});

  // 2. xh|xl = modulate(ln(x), sh_msa, sc_msa)   (sh at ada col 0)
  ln_mod_kernel<<<dim3((N_NODES + 3) / 4), blk, 0, stream>>>(
      x, (const unsigned*)ada, xh, xl);

  // 3. qkv = xm @ w_qkv  -> q(f32) | kv interleaved bf16
  gemm_direct<ProNone, EpiNone, 1, 2><<<dim3(MB, 3), blk, 0, stream>>>(
      xh, xl, Bhi + o_qkv, Blo + o_qkv, qkv, N_NODES, 384, 128,
      ProNone{}, EpiNone{});

  // 4. fused graph attention -> attnb (overlays xh/xl; dead after step 3)
  node_attn_kernel<<<dim3((N_NODES + 3) / 4), blk, 0, stream>>>(Arow, col, qkv, attnb);

  // 5. x1(d_out) = x + g_msa * (attnb @ w_proj + b_proj)   (g_msa at ada col 256)
  gemm_direct<ProNone, EpiResGateB, 0, 0><<<dim3(MB, 1), blk, 0, stream>>>(
      attnb, nullptr, Bhi + o_proj, Blo + o_proj, out, N_NODES, 128, 128,
      ProNone{}, EpiResGateB{b_proj, x, ada + 256});

  // 6. xh|xl = modulate(ln(x1), sh_mlp, sc_mlp)   (sh_mlp at ada col 384;
  //    attnb dead after step 5)
  ln_mod_kernel<<<dim3((N_NODES + 3) / 4), blk, 0, stream>>>(
      out, (const unsigned*)(ada + 384), xh, xl);

  // 7. h1 = gelu(xm @ w_mlp1 + b_mlp1) -> bf16 [N,512] in buf2 (qkv dead)
  gemm_direct<ProNone, EpiGelu, 2, 2><<<dim3(MB, 4), blk, 0, stream>>>(
      xh, xl, Bhi + o_mlp1, Blo + o_mlp1, h1, N_NODES, 512, 128,
      ProNone{}, EpiGelu{b_mlp1});

  // 8. out = x1 + g_mlp * (h1 @ w_mlp2 + b_mlp2)  (g_mlp at ada col 640;
  //    A bf16; in-place element-wise: safe)
  gemm_direct<ProNone, EpiResGateB, 0, 1><<<dim3(MB, 1), blk, 0, stream>>>(
      h1, nullptr, Bhi + o_mlp2, Blo + o_mlp2, out, N_NODES, 128, 512,
      ProNone{}, EpiResGateB{b_mlp2, out, ada + 640});
}